// Round 3
// baseline (392.880 us; speedup 1.0000x reference)
//
#include <hip/hip_runtime.h>
#include <hip/hip_bf16.h>
#include <math.h>

#define DIM 2048
#define BATCH 16384

typedef __attribute__((ext_vector_type(8))) short short8;
typedef __attribute__((ext_vector_type(4))) short short4v;
typedef __attribute__((ext_vector_type(4))) float floatx4;
typedef unsigned short ushort_t;

__device__ __forceinline__ ushort_t f2bf(float f) {
    union { float f; unsigned u; } v; v.f = f;
    unsigned r = v.u + 0x7FFFu + ((v.u >> 16) & 1u);   // RNE
    return (ushort_t)(r >> 16);
}

// ---- band scale vector (length DIM) ----
__global__ void k_scale(const float* __restrict__ fw, const float* __restrict__ kp,
                        float* __restrict__ s) {
    int n = blockIdx.x * blockDim.x + threadIdx.x;
    if (n >= DIM) return;
    float kv = kp[0];
    float f = 1.0f;
    for (int i = 0; i < 30; ++i) {
        long s0 = (long)((double)i       * (double)(DIM - 1) / 30.0);
        long e0 = (long)((double)(i + 1) * (double)(DIM - 1) / 30.0);
        if (n >= s0 && n < e0) {
            if (e0 <= 30)
                f = 1.0f + fw[i] * kv * (1.0f - (float)i / 30.0f);
            else
                f = 1.0f - fw[i] * kv * (1.0f - (float)(i - 30) / 30.0f);
        }
    }
    s[n] = f;
}

// ---- DCT matrix + transpose, bf16, exact integer phase reduction ----
__global__ void k_gen_d(ushort_t* __restrict__ D, ushort_t* __restrict__ Dt) {
    int idx = blockIdx.x * blockDim.x + threadIdx.x;   // DIM*DIM
    int r = idx >> 11;
    int c = idx & (DIM - 1);
    const float w  = 7.6699039394282058e-4f;  // pi/4096
    const float s0 = 0.02209708691207961f;    // sqrt(1/2048)
    const float s1 = 0.03125f;                // sqrt(2/2048)
    int m1 = ((2 * c + 1) * r) & (4 * DIM - 1);
    int m2 = ((2 * r + 1) * c) & (4 * DIM - 1);
    float v1 = __cosf(w * (float)m1) * (r == 0 ? s0 : s1);   // arg < 2pi
    float v2 = __cosf(w * (float)m2) * (c == 0 ? s0 : s1);
    D[idx]  = f2bf(v1);
    Dt[idx] = f2bf(v2);
}

// ---- fp32 -> bf16 casts ----
#define U_W1   262144
#define U_W2    65536
#define U_WH    16384
__global__ void k_cast_w(const float* __restrict__ W1, const float* __restrict__ W2,
                         const float* __restrict__ Wmu, const float* __restrict__ Wlv,
                         ushort_t* __restrict__ W1bf, ushort_t* __restrict__ W2bf,
                         ushort_t* __restrict__ Wcat) {
    int i = blockIdx.x * blockDim.x + threadIdx.x;
    const float* src; ushort_t* dst; int u;
    if (i < U_W1)                    { src = W1;  dst = W1bf;             u = i; }
    else if (i < U_W1 + U_W2)        { src = W2;  dst = W2bf;             u = i - U_W1; }
    else if (i < U_W1 + U_W2 + U_WH) { src = Wmu; dst = Wcat;             u = i - U_W1 - U_W2; }
    else                             { src = Wlv; dst = Wcat + 8 * U_WH;  u = i - U_W1 - U_W2 - U_WH; }
    const float4* p = reinterpret_cast<const float4*>(src) + 2 * (size_t)u;
    float4 a = p[0], b = p[1];
    short8 r;
    r[0] = (short)f2bf(a.x); r[1] = (short)f2bf(a.y);
    r[2] = (short)f2bf(a.z); r[3] = (short)f2bf(a.w);
    r[4] = (short)f2bf(b.x); r[5] = (short)f2bf(b.y);
    r[6] = (short)f2bf(b.z); r[7] = (short)f2bf(b.w);
    *reinterpret_cast<short8*>(dst + 8 * (size_t)u) = r;
}

__global__ void k_cast_x(const float* __restrict__ in, ushort_t* __restrict__ out) {
    int i = blockIdx.x * blockDim.x + threadIdx.x;
    const float4* p = reinterpret_cast<const float4*>(in) + 2 * (size_t)i;
    float4 a = p[0], b = p[1];
    short8 r;
    r[0] = (short)f2bf(a.x); r[1] = (short)f2bf(a.y);
    r[2] = (short)f2bf(a.z); r[3] = (short)f2bf(a.w);
    r[4] = (short)f2bf(b.x); r[5] = (short)f2bf(b.y);
    r[6] = (short)f2bf(b.z); r[7] = (short)f2bf(b.w);
    *reinterpret_cast<short8*>(out + 8 * (size_t)i) = r;
}

// ---- split-K reduce: out = bf16( (P0+P1+P2+P3) [* scale[col]] ) ----
__global__ void k_red(const float* __restrict__ P, ushort_t* __restrict__ out,
                      const float* __restrict__ scale, int n4, int n4row) {
    int i = blockIdx.x * blockDim.x + threadIdx.x;   // float4 index
    const float4* p = reinterpret_cast<const float4*>(P);
    float4 a = p[i], b = p[i + n4], c = p[i + 2 * n4], d = p[i + 3 * n4];
    float4 s;
    s.x = a.x + b.x + c.x + d.x;
    s.y = a.y + b.y + c.y + d.y;
    s.z = a.z + b.z + c.z + d.z;
    s.w = a.w + b.w + c.w + d.w;
    if (scale) {
        float4 sc = reinterpret_cast<const float4*>(scale)[i & (n4row - 1)];
        s.x *= sc.x; s.y *= sc.y; s.z *= sc.z; s.w *= sc.w;
    }
    short4v o;
    o[0] = (short)f2bf(s.x); o[1] = (short)f2bf(s.y);
    o[2] = (short)f2bf(s.z); o[3] = (short)f2bf(s.w);
    *reinterpret_cast<short4v*>(out + 4 * (size_t)i) = o;
}

// ---- OLD GEMM core (serial stage->drain->compute), kept for split-K G0/G1 ----
template<int TM, int TN, int BK, int EPI, bool SK4>
__device__ __forceinline__ void gemm_core(
        const ushort_t* __restrict__ A, const ushort_t* __restrict__ B,
        ushort_t* __restrict__ Cb, float* __restrict__ Cf,
        const float* __restrict__ ep0, const float* __restrict__ ep1,
        int M, int N, int K, int KC) {
    constexpr int BM = 32 * TM;
    constexpr int BN = 32 * TN;
    constexpr int SEGS = BK / 8;
    constexpr int RSH  = (BK == 32) ? 1 : 0;
    constexpr int SSH  = (SEGS == 4) ? 2 : 3;
    __shared__ __align__(16) ushort_t As[BM * BK];
    __shared__ __align__(16) ushort_t Bs[BN * BK];

    const int tid  = threadIdx.x;
    const int lane = tid & 63;
    const int wave = tid >> 6;
    const int wm   = wave >> 1;
    const int wn   = wave & 1;
    const int q    = lane >> 4;
    const int l16  = lane & 15;

    const int tilesM = M / BM;
    const int tilesN = N / BN;
    int bid = (int)blockIdx.x;
    int sk = 0;
    if constexpr (SK4) { int nt = tilesM * tilesN; sk = bid / nt; bid = bid % nt; }
    const int xcd = bid & 7;
    const int j   = bid >> 3;
    const int bm  = xcd * (tilesM >> 3) + j / tilesN;
    const int bn  = j % tilesN;

    floatx4 acc[TM][TN];
    #pragma unroll
    for (int i = 0; i < TM; ++i)
        #pragma unroll
        for (int jj = 0; jj < TN; ++jj)
            acc[i][jj] = (floatx4){0.f, 0.f, 0.f, 0.f};

    const long aBase = (long)bm * BM * K + (long)sk * KC;
    const long bBase = (long)bn * BN * K + (long)sk * KC;
    const int  KLOOP = SK4 ? KC : K;

    for (int kt = 0; kt < KLOOP; kt += BK) {
        __syncthreads();
        #pragma unroll
        for (int i = 0; i < BM * BK / 2048; ++i) {
            int idx = tid + i * 256;
            int row = idx >> SSH, seg = idx & (SEGS - 1);
            int gseg = seg ^ ((row >> RSH) & (SEGS - 1));
            const ushort_t* g = A + aBase + (long)row * K + kt + gseg * 8;
            __builtin_amdgcn_global_load_lds(
                (const __attribute__((address_space(1))) void*)g,
                (__attribute__((address_space(3))) void*)(As + idx * 8),
                16, 0, 0);
        }
        #pragma unroll
        for (int i = 0; i < BN * BK / 2048; ++i) {
            int idx = tid + i * 256;
            int row = idx >> SSH, seg = idx & (SEGS - 1);
            int gseg = seg ^ ((row >> RSH) & (SEGS - 1));
            const ushort_t* g = B + bBase + (long)row * K + kt + gseg * 8;
            __builtin_amdgcn_global_load_lds(
                (const __attribute__((address_space(1))) void*)g,
                (__attribute__((address_space(3))) void*)(Bs + idx * 8),
                16, 0, 0);
        }
        __syncthreads();

        #pragma unroll
        for (int ks = 0; ks < BK / 32; ++ks) {
            short8 af[TM], bfr[TN];
            #pragma unroll
            for (int t = 0; t < TM; ++t) {
                int srow = wm * TM * 16 + t * 16 + l16;
                int rseg = (ks * 4 + q) ^ ((srow >> RSH) & (SEGS - 1));
                af[t] = *reinterpret_cast<const short8*>(&As[srow * BK + rseg * 8]);
            }
            #pragma unroll
            for (int t = 0; t < TN; ++t) {
                int srow = wn * TN * 16 + t * 16 + l16;
                int rseg = (ks * 4 + q) ^ ((srow >> RSH) & (SEGS - 1));
                bfr[t] = *reinterpret_cast<const short8*>(&Bs[srow * BK + rseg * 8]);
            }
            #pragma unroll
            for (int i = 0; i < TM; ++i)
                #pragma unroll
                for (int jj = 0; jj < TN; ++jj)
                    acc[i][jj] = __builtin_amdgcn_mfma_f32_16x16x32_bf16(
                        af[i], bfr[jj], acc[i][jj], 0, 0, 0);
        }
    }

    #pragma unroll
    for (int i = 0; i < TM; ++i) {
        #pragma unroll
        for (int jj = 0; jj < TN; ++jj) {
            #pragma unroll
            for (int r = 0; r < 4; ++r) {
                int row = bm * BM + wm * TM * 16 + i * 16 + q * 4 + r;
                int col = bn * BN + wn * TN * 16 + jj * 16 + l16;
                float v = acc[i][jj][r];
                if constexpr (EPI == 2) {
                    v += ep0[col];
                    v = v > 0.f ? v : 0.f;
                    Cb[(long)row * N + col] = f2bf(v);
                } else if constexpr (EPI == 3) {
                    const int half = N >> 1;
                    if (col < half)
                        Cf[(long)row * half + col] = v + ep0[col];
                    else
                        Cf[(long)M * half + (long)row * half + (col - half)] = v + ep1[col - half];
                } else {
                    Cf[(long)sk * M * N + (long)row * N + col] = v;
                }
            }
        }
    }
}

// =====================================================================
// R3: G2 with register-level read-ahead (software pipeline depth 2 on
// LDS->reg, depth 3 on HBM->LDS via ring-4).
// Iteration t:  [regs(t) already loaded; tile t+1 landed+published]
//   issue 12 ds_read for tile t+1 (slot (t+1)&3)   -> runs on LDS pipe
//   issue 4 DMA stage of tile t+3                  -> runs on VMEM
//   32 MFMA on regs(t)  (zero lgkm dependence -> back-to-back)
//   lgkmcnt(0)+sched_barrier(0)  (regs t+1 in; pins reads above barrier)
//   vmcnt(4)  (tile t+2 landed; tile t+3's 4 loads may remain in flight)
//   s_barrier (publishes tile t+2; WAR fence for slot reuse)
// Race-safety:
//  RAW(DMA): end of iter t-1 vmcnt(4)+barrier guarantees tile t+1 fully
//            landed before any wave's iter-t reads of slot (t+1)&3.
//  WAR(DMA): slot (t+1)&3 is next DMA-written for tile t+5 in iter t+2,
//            two barriers after the lgkmcnt(0) that drains these reads.
// =====================================================================
__global__ __launch_bounds__(512, 2) void g2_256(const ushort_t* __restrict__ A,
        const ushort_t* __restrict__ B, ushort_t* __restrict__ Cb,
        const float* __restrict__ bias, int M, int N, int K) {
    constexpr int BM = 256, BN = 256, BK = 32;
    __shared__ __align__(16) ushort_t As[4][BM * BK];   // 4 x 16 KiB
    __shared__ __align__(16) ushort_t Bs[4][BN * BK];   // 4 x 16 KiB

    const int tid  = threadIdx.x;
    const int lane = tid & 63;
    const int wave = tid >> 6;
    const int wm   = wave >> 2;         // 0..1
    const int wn   = wave & 3;          // 0..3
    const int q    = lane >> 4;
    const int l16  = lane & 15;

    const int tilesM = M / BM;          // 64
    const int tilesN = N / BN;          // 4
    int bid = (int)blockIdx.x;
    const int xcd = bid & 7;
    const int jb  = bid >> 3;
    const int bm  = xcd * (tilesM >> 3) + jb / tilesN;
    const int bn  = jb % tilesN;
    const int NT  = K / BK;             // 64 (even)

    const long aBase = (long)bm * BM * K;
    const long bBase = (long)bn * BN * K;

    floatx4 acc[8][4];
    #pragma unroll
    for (int i = 0; i < 8; ++i)
        #pragma unroll
        for (int j = 0; j < 4; ++j)
            acc[i][j] = (floatx4){0.f, 0.f, 0.f, 0.f};

#define STAGE_A(t) do { int _sl = (t) & 3;                                          \
        _Pragma("unroll")                                                           \
        for (int _g = 0; _g < 2; ++_g) {                                            \
            int _idx = _g * 512 + tid;                                              \
            int _row = _idx >> 2, _seg = _idx & 3;                                  \
            int _gs = _seg ^ ((_row >> 1) & 3);                                     \
            const ushort_t* _gp = A + aBase + (long)_row * K + (t) * BK + _gs * 8;  \
            __builtin_amdgcn_global_load_lds(                                       \
                (const __attribute__((address_space(1))) void*)_gp,                 \
                (__attribute__((address_space(3))) void*)(&As[_sl][_idx * 8]),      \
                16, 0, 0);                                                          \
        } } while (0)
#define STAGE_B(t) do { int _sl = (t) & 3;                                          \
        _Pragma("unroll")                                                           \
        for (int _g = 0; _g < 2; ++_g) {                                            \
            int _idx = _g * 512 + tid;                                              \
            int _row = _idx >> 2, _seg = _idx & 3;                                  \
            int _gs = _seg ^ ((_row >> 1) & 3);                                     \
            const ushort_t* _gp = B + bBase + (long)_row * K + (t) * BK + _gs * 8;  \
            __builtin_amdgcn_global_load_lds(                                       \
                (const __attribute__((address_space(1))) void*)_gp,                 \
                (__attribute__((address_space(3))) void*)(&Bs[_sl][_idx * 8]),      \
                16, 0, 0);                                                          \
        } } while (0)

// load 12 fragments for tile (tt) into the named register arrays
#define READF(tt, BF, ALO, AHI) do { const int _slot = (tt) & 3;                    \
        _Pragma("unroll")                                                           \
        for (int _j = 0; _j < 4; ++_j) {                                            \
            int _sr = wn * 64 + _j * 16 + l16;                                      \
            int _rs = q ^ ((_sr >> 1) & 3);                                         \
            BF[_j] = *reinterpret_cast<const short8*>(&Bs[_slot][_sr * BK + _rs * 8]); \
        }                                                                           \
        _Pragma("unroll")                                                           \
        for (int _i = 0; _i < 4; ++_i) {                                            \
            int _sr = wm * 128 + _i * 16 + l16;                                     \
            int _rs = q ^ ((_sr >> 1) & 3);                                         \
            ALO[_i] = *reinterpret_cast<const short8*>(&As[_slot][_sr * BK + _rs * 8]); \
        }                                                                           \
        _Pragma("unroll")                                                           \
        for (int _i = 0; _i < 4; ++_i) {                                            \
            int _sr = wm * 128 + 64 + _i * 16 + l16;                                \
            int _rs = q ^ ((_sr >> 1) & 3);                                         \
            AHI[_i] = *reinterpret_cast<const short8*>(&As[_slot][_sr * BK + _rs * 8]); \
        }                                                                           \
    } while (0)

#define MFMA_SET(BF, ALO, AHI) do {                                                 \
        __builtin_amdgcn_s_setprio(1);                                              \
        _Pragma("unroll")                                                           \
        for (int _i = 0; _i < 4; ++_i)                                              \
            _Pragma("unroll")                                                       \
            for (int _j = 0; _j < 4; ++_j)                                          \
                acc[_i][_j] = __builtin_amdgcn_mfma_f32_16x16x32_bf16(              \
                    ALO[_i], BF[_j], acc[_i][_j], 0, 0, 0);                         \
        _Pragma("unroll")                                                           \
        for (int _i = 0; _i < 4; ++_i)                                              \
            _Pragma("unroll")                                                       \
            for (int _j = 0; _j < 4; ++_j)                                          \
                acc[4 + _i][_j] = __builtin_amdgcn_mfma_f32_16x16x32_bf16(          \
                    AHI[_i], BF[_j], acc[4 + _i][_j], 0, 0, 0);                     \
        __builtin_amdgcn_s_setprio(0);                                              \
    } while (0)

#define ENDSYNC4  do { asm volatile("s_waitcnt lgkmcnt(0)" ::: "memory");           \
        __builtin_amdgcn_sched_barrier(0);                                          \
        asm volatile("s_waitcnt vmcnt(4)" ::: "memory");                            \
        __builtin_amdgcn_s_barrier(); asm volatile("" ::: "memory"); } while (0)
#define ENDSYNC0  do { asm volatile("s_waitcnt lgkmcnt(0)" ::: "memory");           \
        __builtin_amdgcn_sched_barrier(0);                                          \
        asm volatile("s_waitcnt vmcnt(0)" ::: "memory");                            \
        __builtin_amdgcn_s_barrier(); asm volatile("" ::: "memory"); } while (0)
#define ENDSYNCL  do { asm volatile("s_waitcnt lgkmcnt(0)" ::: "memory");           \
        __builtin_amdgcn_sched_barrier(0);                                          \
        __builtin_amdgcn_s_barrier(); asm volatile("" ::: "memory"); } while (0)

    short8 bf0[4], alo0[4], ahi0[4];
    short8 bf1[4], alo1[4], ahi1[4];

    // prologue: stage tiles 0,1,2; load regs(0); ensure tile1 landed+published
    STAGE_A(0); STAGE_B(0);
    STAGE_A(1); STAGE_B(1);
    STAGE_A(2); STAGE_B(2);
    asm volatile("s_waitcnt vmcnt(8)" ::: "memory");
    __builtin_amdgcn_s_barrier();
    asm volatile("" ::: "memory");
    READF(0, bf0, alo0, ahi0);
    asm volatile("s_waitcnt vmcnt(4)" ::: "memory");
    __builtin_amdgcn_s_barrier();
    asm volatile("" ::: "memory");

    // main loop: pairs t=(0,1),(2,3),...,(58,59); all stage (t+3 <= 62)
    for (int t = 0; t < NT - 4; t += 2) {
        READF(t + 1, bf1, alo1, ahi1);
        STAGE_A(t + 3); STAGE_B(t + 3);
        MFMA_SET(bf0, alo0, ahi0);
        ENDSYNC4;
        READF(t + 2, bf0, alo0, ahi0);
        STAGE_A(t + 4); STAGE_B(t + 4);
        MFMA_SET(bf1, alo1, ahi1);
        ENDSYNC4;
    }
    // t = 60: stage 63 (last)
    READF(61, bf1, alo1, ahi1);
    STAGE_A(63); STAGE_B(63);
    MFMA_SET(bf0, alo0, ahi0);
    ENDSYNC4;
    // t = 61: need tile 63 landed at end
    READF(62, bf0, alo0, ahi0);
    MFMA_SET(bf1, alo1, ahi1);
    ENDSYNC0;
    // t = 62
    READF(63, bf1, alo1, ahi1);
    MFMA_SET(bf0, alo0, ahi0);
    ENDSYNCL;
    // t = 63
    MFMA_SET(bf1, alo1, ahi1);

#undef ENDSYNCL
#undef ENDSYNC0
#undef ENDSYNC4
#undef MFMA_SET
#undef READF
#undef STAGE_A
#undef STAGE_B

    // epilogue: bias + relu -> bf16
    float bsv[4];
    #pragma unroll
    for (int j = 0; j < 4; ++j)
        bsv[j] = bias[bn * BN + wn * 64 + j * 16 + l16];
    #pragma unroll
    for (int i = 0; i < 8; ++i) {
        int row = bm * BM + wm * 128 + i * 16 + q * 4;
        #pragma unroll
        for (int j = 0; j < 4; ++j) {
            int col = bn * BN + wn * 64 + j * 16 + l16;
            #pragma unroll
            for (int r = 0; r < 4; ++r) {
                float v = acc[i][j][r] + bsv[j];
                v = v > 0.f ? v : 0.f;
                Cb[(long)(row + r) * N + col] = f2bf(v);
            }
        }
    }
}

// ---- 128x128 tile pipelined core: 256 thr (4 waves 2x2), BK=32, ring-4 (64 KiB) ----
// EPI 2: +bias,relu->bf16 | 3: +bias split fp32 (mu|logvar)
template<int EPI>
__device__ __forceinline__ void gemm128_v2(
        const ushort_t* __restrict__ A, const ushort_t* __restrict__ B,
        ushort_t* __restrict__ Cb, float* __restrict__ Cf,
        const float* __restrict__ ep0, const float* __restrict__ ep1,
        int M, int N, int K) {
    constexpr int BM = 128, BN = 128, BK = 32;
    __shared__ __align__(16) ushort_t As[4][BM * BK];   // 4 x 8 KiB
    __shared__ __align__(16) ushort_t Bs[4][BN * BK];   // 4 x 8 KiB

    const int tid  = threadIdx.x;
    const int lane = tid & 63;
    const int wave = tid >> 6;
    const int wm   = wave >> 1;
    const int wn   = wave & 1;
    const int q    = lane >> 4;
    const int l16  = lane & 15;

    const int tilesM = M / BM;
    const int tilesN = N / BN;
    int bid = (int)blockIdx.x;
    const int xcd = bid & 7;
    const int jb  = bid >> 3;
    const int bm  = xcd * (tilesM >> 3) + jb / tilesN;
    const int bn  = jb % tilesN;
    const int NT  = K / BK;

    const long aBase = (long)bm * BM * K;
    const long bBase = (long)bn * BN * K;

    floatx4 acc[4][4];
    #pragma unroll
    for (int i = 0; i < 4; ++i)
        #pragma unroll
        for (int j = 0; j < 4; ++j)
            acc[i][j] = (floatx4){0.f, 0.f, 0.f, 0.f};

#define STAGE_A(t) do { int _sl = (t) & 3;                                          \
        _Pragma("unroll")                                                           \
        for (int _g = 0; _g < 2; ++_g) {                                            \
            int _idx = _g * 256 + tid;                                              \
            int _row = _idx >> 2, _seg = _idx & 3;                                  \
            int _gs = _seg ^ ((_row >> 1) & 3);                                     \
            const ushort_t* _gp = A + aBase + (long)_row * K + (t) * BK + _gs * 8;  \
            __builtin_amdgcn_global_load_lds(                                       \
                (const __attribute__((address_space(1))) void*)_gp,                 \
                (__attribute__((address_space(3))) void*)(&As[_sl][_idx * 8]),      \
                16, 0, 0);                                                          \
        } } while (0)
#define STAGE_B(t) do { int _sl = (t) & 3;                                          \
        _Pragma("unroll")                                                           \
        for (int _g = 0; _g < 2; ++_g) {                                            \
            int _idx = _g * 256 + tid;                                              \
            int _row = _idx >> 2, _seg = _idx & 3;                                  \
            int _gs = _seg ^ ((_row >> 1) & 3);                                     \
            const ushort_t* _gp = B + bBase + (long)_row * K + (t) * BK + _gs * 8;  \
            __builtin_amdgcn_global_load_lds(                                       \
                (const __attribute__((address_space(1))) void*)_gp,                 \
                (__attribute__((address_space(3))) void*)(&Bs[_sl][_idx * 8]),      \
                16, 0, 0);                                                          \
        } } while (0)

    STAGE_A(0); STAGE_B(0);
    STAGE_A(1); STAGE_B(1);
    STAGE_A(2); STAGE_B(2);
    asm volatile("s_waitcnt vmcnt(8)" ::: "memory");
    __builtin_amdgcn_s_barrier();
    asm volatile("" ::: "memory");

#define KTILE(tt, DOSTAGE, WAITOP) do {                                             \
        const int _slot = (tt) & 3;                                                 \
        short8 _bf[4], _af[4];                                                      \
        _Pragma("unroll")                                                           \
        for (int _j = 0; _j < 4; ++_j) {                                            \
            int _sr = wn * 64 + _j * 16 + l16;                                      \
            int _rs = q ^ ((_sr >> 1) & 3);                                         \
            _bf[_j] = *reinterpret_cast<const short8*>(&Bs[_slot][_sr * BK + _rs * 8]); \
        }                                                                           \
        _Pragma("unroll")                                                           \
        for (int _i = 0; _i < 4; ++_i) {                                            \
            int _sr = wm * 64 + _i * 16 + l16;                                      \
            int _rs = q ^ ((_sr >> 1) & 3);                                         \
            _af[_i] = *reinterpret_cast<const short8*>(&As[_slot][_sr * BK + _rs * 8]); \
        }                                                                           \
        if (DOSTAGE) { STAGE_A((tt) + 3); STAGE_B((tt) + 3); }                      \
        __builtin_amdgcn_s_setprio(1);                                              \
        _Pragma("unroll")                                                           \
        for (int _i = 0; _i < 4; ++_i)                                              \
            _Pragma("unroll")                                                       \
            for (int _j = 0; _j < 4; ++_j)                                          \
                acc[_i][_j] = __builtin_amdgcn_mfma_f32_16x16x32_bf16(              \
                    _af[_i], _bf[_j], acc[_i][_j], 0, 0, 0);                        \
        __builtin_amdgcn_s_setprio(0);                                              \
        asm volatile("s_waitcnt lgkmcnt(0)" ::: "memory");                          \
        __builtin_amdgcn_sched_barrier(0);                                          \
        WAITOP;                                                                     \
        __builtin_amdgcn_s_barrier();                                               \
        asm volatile("" ::: "memory");                                              \
    } while (0)

    int t = 0;
    for (; t < NT - 3; ++t) {
        KTILE(t, true, asm volatile("s_waitcnt vmcnt(8)" ::: "memory"));
    }
    KTILE(t, false, asm volatile("s_waitcnt vmcnt(4)" ::: "memory")); ++t;
    KTILE(t, false, asm volatile("s_waitcnt vmcnt(0)" ::: "memory")); ++t;
    KTILE(t, false, (void)0);

#undef KTILE
#undef STAGE_A
#undef STAGE_B

    #pragma unroll
    for (int i = 0; i < 4; ++i) {
        #pragma unroll
        for (int jj = 0; jj < 4; ++jj) {
            #pragma unroll
            for (int r = 0; r < 4; ++r) {
                int row = bm * BM + wm * 64 + i * 16 + q * 4 + r;
                int col = bn * BN + wn * 64 + jj * 16 + l16;
                float v = acc[i][jj][r];
                if constexpr (EPI == 2) {
                    v += ep0[col];
                    v = v > 0.f ? v : 0.f;
                    Cb[(long)row * N + col] = f2bf(v);
                } else {
                    const int half = N >> 1;
                    v += (col < half) ? ep0[col] : ep1[col - half];
                    if (col < half)
                        Cf[(long)row * half + col] = v;
                    else
                        Cf[(long)M * half + (long)row * half + (col - half)] = v;
                }
            }
        }
    }
}

// named wrappers (rocprof per-stage attribution)
__global__ __launch_bounds__(256) void g0p_sk(const ushort_t* A, const ushort_t* B,
        float* P, int M, int N, int K, int KC) {
    gemm_core<4, 4, 32, 4, true>(A, B, nullptr, P, nullptr, nullptr, M, N, K, KC);
}
__global__ __launch_bounds__(256) void g1p_sk(const ushort_t* A, const ushort_t* B,
        float* P, int M, int N, int K, int KC) {
    gemm_core<4, 4, 32, 4, true>(A, B, nullptr, P, nullptr, nullptr, M, N, K, KC);
}
__global__ __launch_bounds__(256, 2) void g3_h2(const ushort_t* A, const ushort_t* B,
        ushort_t* Cb, const float* ep0, int M, int N, int K) {
    gemm128_v2<2>(A, B, Cb, nullptr, ep0, nullptr, M, N, K);
}
__global__ __launch_bounds__(256, 2) void g4_head(const ushort_t* A, const ushort_t* B,
        float* Cf, const float* ep0, const float* ep1, int M, int N, int K) {
    gemm128_v2<3>(A, B, nullptr, Cf, ep0, ep1, M, N, K);
}

extern "C" void kernel_launch(void* const* d_in, const int* in_sizes, int n_in,
                              void* d_out, int out_size, void* d_ws, size_t ws_size,
                              hipStream_t stream) {
    const float* x   = (const float*)d_in[0];
    const float* fw  = (const float*)d_in[1];
    const float* kp  = (const float*)d_in[2];
    const float* W1  = (const float*)d_in[3];
    const float* b1  = (const float*)d_in[4];
    const float* W2  = (const float*)d_in[5];
    const float* b2  = (const float*)d_in[6];
    const float* Wmu = (const float*)d_in[7];
    const float* bmu = (const float*)d_in[8];
    const float* Wlv = (const float*)d_in[9];
    const float* blv = (const float*)d_in[10];
    float* out = (float*)d_out;

    char* ws = (char*)d_ws;
    const size_t MB = 1024 * 1024;
    // timeline-safe overlays (total 118.01 MB, within proven R0 footprint):
    ushort_t* W1bf = (ushort_t*)(ws + 0);         //  4 MB   dead after g0p
    ushort_t* Dbf  = (ushort_t*)(ws + 4   * MB);  //  8 MB   dead after g0p
    ushort_t* Dtbf = (ushort_t*)(ws + 12  * MB);  //  8 MB   dead after g1p
    ushort_t* T1sT = (ushort_t*)(ws + 20  * MB);  //  4 MB   dead after g1p
    ushort_t* H1   = (ushort_t*)(ws + 0);         // 32 MB   written by g2 (overlays above)
    float*    P    = (float*)   (ws + 32  * MB);  // 32 MB   dead after k_red #2
    ushort_t* Xbf  = (ushort_t*)(ws + 32  * MB);  // 64 MB   written after P dead (32..96)
    ushort_t* H2   = (ushort_t*)(ws + 96  * MB);  // 16 MB
    ushort_t* M1T  = (ushort_t*)(ws + 112 * MB);  //  4 MB
    ushort_t* W2bf = (ushort_t*)(ws + 116 * MB);  //  1 MB
    ushort_t* Wcat = (ushort_t*)(ws + 117 * MB);  // 0.5 MB
    float*    svec = (float*)   (ws + 118 * MB);  //  8 KB

    hipLaunchKernelGGL(k_scale, dim3(DIM / 256), dim3(256), 0, stream, fw, kp, svec);
    hipLaunchKernelGGL(k_gen_d, dim3(DIM * DIM / 256), dim3(256), 0, stream, Dbf, Dtbf);
    hipLaunchKernelGGL(k_cast_w, dim3((U_W1 + U_W2 + 2 * U_WH) / 256), dim3(256), 0, stream,
                       W1, W2, Wmu, Wlv, W1bf, W2bf, Wcat);

    // G0 (split-K=4): P[sk] = W1bf @ Dbf^T chunk   (1024 x 2048, KC=512)
    hipLaunchKernelGGL(g0p_sk, dim3(8 * 16 * 4), dim3(256), 0, stream,
                       W1bf, Dbf, P, 1024, 2048, 2048, 512);
    // reduce + scale -> T1sT
    hipLaunchKernelGGL(k_red, dim3(1024 * 2048 / 4 / 256), dim3(256), 0, stream,
                       P, T1sT, svec, 1024 * 2048 / 4, 2048 / 4);
    // G1 (split-K=4): P[sk] = T1sT @ Dtbf^T chunk  (1024 x 2048, KC=512)
    hipLaunchKernelGGL(g1p_sk, dim3(8 * 16 * 4), dim3(256), 0, stream,
                       T1sT, Dtbf, P, 1024, 2048, 2048, 512);
    // reduce -> M1T
    hipLaunchKernelGGL(k_red, dim3(1024 * 2048 / 4 / 256), dim3(256), 0, stream,
                       P, M1T, nullptr, 1024 * 2048 / 4, 2048 / 4);

    // X cast (after P is dead; Xbf overlays P region)
    hipLaunchKernelGGL(k_cast_x, dim3(BATCH * DIM / 8 / 256), dim3(256), 0, stream, x, Xbf);

    // G2: H1 = relu(Xbf @ M1 + b1)   (16384 x 1024, K=2048) — 256² reg-prefetch pipeline
    hipLaunchKernelGGL(g2_256, dim3((BATCH / 256) * (1024 / 256)), dim3(512), 0, stream,
                       Xbf, M1T, H1, b1, BATCH, 1024, 2048);
    // G3: H2 = relu(H1 @ W2^T + b2)  (16384 x 512, K=1024) — 128² ring-4 pipelined
    hipLaunchKernelGGL(g3_h2, dim3((BATCH / 128) * (512 / 128)), dim3(256), 0, stream,
                       H1, W2bf, H2, b2, BATCH, 512, 1024);
    // G4: [mu | logvar] = H2 @ Wcat^T + bias, fp32 split (16384 x 512, K=512)
    hipLaunchKernelGGL(g4_head, dim3((BATCH / 128) * (512 / 128)), dim3(256), 0, stream,
                       H2, Wcat, out, bmu, blv, BATCH, 512, 512);

    (void)in_sizes; (void)n_in; (void)out_size; (void)ws_size;
}

// Round 4
// 386.007 us; speedup vs baseline: 1.0178x; 1.0178x over previous
//
#include <hip/hip_runtime.h>
#include <hip/hip_bf16.h>
#include <math.h>

#define DIM 2048
#define BATCH 16384

typedef __attribute__((ext_vector_type(8))) short short8;
typedef __attribute__((ext_vector_type(4))) short short4v;
typedef __attribute__((ext_vector_type(4))) float floatx4;
typedef unsigned short ushort_t;

__device__ __forceinline__ ushort_t f2bf(float f) {
    union { float f; unsigned u; } v; v.f = f;
    unsigned r = v.u + 0x7FFFu + ((v.u >> 16) & 1u);   // RNE
    return (ushort_t)(r >> 16);
}

// ---- band scale vector (length DIM) ----
__global__ void k_scale(const float* __restrict__ fw, const float* __restrict__ kp,
                        float* __restrict__ s) {
    int n = blockIdx.x * blockDim.x + threadIdx.x;
    if (n >= DIM) return;
    float kv = kp[0];
    float f = 1.0f;
    for (int i = 0; i < 30; ++i) {
        long s0 = (long)((double)i       * (double)(DIM - 1) / 30.0);
        long e0 = (long)((double)(i + 1) * (double)(DIM - 1) / 30.0);
        if (n >= s0 && n < e0) {
            if (e0 <= 30)
                f = 1.0f + fw[i] * kv * (1.0f - (float)i / 30.0f);
            else
                f = 1.0f - fw[i] * kv * (1.0f - (float)(i - 30) / 30.0f);
        }
    }
    s[n] = f;
}

// ---- DCT matrix + transpose, bf16, exact integer phase reduction ----
__global__ void k_gen_d(ushort_t* __restrict__ D, ushort_t* __restrict__ Dt) {
    int idx = blockIdx.x * blockDim.x + threadIdx.x;   // DIM*DIM
    int r = idx >> 11;
    int c = idx & (DIM - 1);
    const float w  = 7.6699039394282058e-4f;  // pi/4096
    const float s0 = 0.02209708691207961f;    // sqrt(1/2048)
    const float s1 = 0.03125f;                // sqrt(2/2048)
    int m1 = ((2 * c + 1) * r) & (4 * DIM - 1);
    int m2 = ((2 * r + 1) * c) & (4 * DIM - 1);
    float v1 = __cosf(w * (float)m1) * (r == 0 ? s0 : s1);   // arg < 2pi
    float v2 = __cosf(w * (float)m2) * (c == 0 ? s0 : s1);
    D[idx]  = f2bf(v1);
    Dt[idx] = f2bf(v2);
}

// ---- fp32 -> bf16 casts ----
#define U_W1   262144
#define U_W2    65536
#define U_WH    16384
__global__ void k_cast_w(const float* __restrict__ W1, const float* __restrict__ W2,
                         const float* __restrict__ Wmu, const float* __restrict__ Wlv,
                         ushort_t* __restrict__ W1bf, ushort_t* __restrict__ W2bf,
                         ushort_t* __restrict__ Wcat) {
    int i = blockIdx.x * blockDim.x + threadIdx.x;
    const float* src; ushort_t* dst; int u;
    if (i < U_W1)                    { src = W1;  dst = W1bf;             u = i; }
    else if (i < U_W1 + U_W2)        { src = W2;  dst = W2bf;             u = i - U_W1; }
    else if (i < U_W1 + U_W2 + U_WH) { src = Wmu; dst = Wcat;             u = i - U_W1 - U_W2; }
    else                             { src = Wlv; dst = Wcat + 8 * U_WH;  u = i - U_W1 - U_W2 - U_WH; }
    const float4* p = reinterpret_cast<const float4*>(src) + 2 * (size_t)u;
    float4 a = p[0], b = p[1];
    short8 r;
    r[0] = (short)f2bf(a.x); r[1] = (short)f2bf(a.y);
    r[2] = (short)f2bf(a.z); r[3] = (short)f2bf(a.w);
    r[4] = (short)f2bf(b.x); r[5] = (short)f2bf(b.y);
    r[6] = (short)f2bf(b.z); r[7] = (short)f2bf(b.w);
    *reinterpret_cast<short8*>(dst + 8 * (size_t)u) = r;
}

__global__ void k_cast_x(const float* __restrict__ in, ushort_t* __restrict__ out) {
    int i = blockIdx.x * blockDim.x + threadIdx.x;
    const float4* p = reinterpret_cast<const float4*>(in) + 2 * (size_t)i;
    float4 a = p[0], b = p[1];
    short8 r;
    r[0] = (short)f2bf(a.x); r[1] = (short)f2bf(a.y);
    r[2] = (short)f2bf(a.z); r[3] = (short)f2bf(a.w);
    r[4] = (short)f2bf(b.x); r[5] = (short)f2bf(b.y);
    r[6] = (short)f2bf(b.z); r[7] = (short)f2bf(b.w);
    *reinterpret_cast<short8*>(out + 8 * (size_t)i) = r;
}

// ---- split-K reduce: out = bf16( (P0+P1+P2+P3) [* scale[col]] ) ----
__global__ void k_red(const float* __restrict__ P, ushort_t* __restrict__ out,
                      const float* __restrict__ scale, int n4, int n4row) {
    int i = blockIdx.x * blockDim.x + threadIdx.x;   // float4 index
    const float4* p = reinterpret_cast<const float4*>(P);
    float4 a = p[i], b = p[i + n4], c = p[i + 2 * n4], d = p[i + 3 * n4];
    float4 s;
    s.x = a.x + b.x + c.x + d.x;
    s.y = a.y + b.y + c.y + d.y;
    s.z = a.z + b.z + c.z + d.z;
    s.w = a.w + b.w + c.w + d.w;
    if (scale) {
        float4 sc = reinterpret_cast<const float4*>(scale)[i & (n4row - 1)];
        s.x *= sc.x; s.y *= sc.y; s.z *= sc.z; s.w *= sc.w;
    }
    short4v o;
    o[0] = (short)f2bf(s.x); o[1] = (short)f2bf(s.y);
    o[2] = (short)f2bf(s.z); o[3] = (short)f2bf(s.w);
    *reinterpret_cast<short4v*>(out + 4 * (size_t)i) = o;
}

// ---- OLD GEMM core (serial stage->drain->compute), kept for split-K G0/G1 ----
template<int TM, int TN, int BK, int EPI, bool SK4>
__device__ __forceinline__ void gemm_core(
        const ushort_t* __restrict__ A, const ushort_t* __restrict__ B,
        ushort_t* __restrict__ Cb, float* __restrict__ Cf,
        const float* __restrict__ ep0, const float* __restrict__ ep1,
        int M, int N, int K, int KC) {
    constexpr int BM = 32 * TM;
    constexpr int BN = 32 * TN;
    constexpr int SEGS = BK / 8;
    constexpr int RSH  = (BK == 32) ? 1 : 0;
    constexpr int SSH  = (SEGS == 4) ? 2 : 3;
    __shared__ __align__(16) ushort_t As[BM * BK];
    __shared__ __align__(16) ushort_t Bs[BN * BK];

    const int tid  = threadIdx.x;
    const int lane = tid & 63;
    const int wave = tid >> 6;
    const int wm   = wave >> 1;
    const int wn   = wave & 1;
    const int q    = lane >> 4;
    const int l16  = lane & 15;

    const int tilesM = M / BM;
    const int tilesN = N / BN;
    int bid = (int)blockIdx.x;
    int sk = 0;
    if constexpr (SK4) { int nt = tilesM * tilesN; sk = bid / nt; bid = bid % nt; }
    const int xcd = bid & 7;
    const int j   = bid >> 3;
    const int bm  = xcd * (tilesM >> 3) + j / tilesN;
    const int bn  = j % tilesN;

    floatx4 acc[TM][TN];
    #pragma unroll
    for (int i = 0; i < TM; ++i)
        #pragma unroll
        for (int jj = 0; jj < TN; ++jj)
            acc[i][jj] = (floatx4){0.f, 0.f, 0.f, 0.f};

    const long aBase = (long)bm * BM * K + (long)sk * KC;
    const long bBase = (long)bn * BN * K + (long)sk * KC;
    const int  KLOOP = SK4 ? KC : K;

    for (int kt = 0; kt < KLOOP; kt += BK) {
        __syncthreads();
        #pragma unroll
        for (int i = 0; i < BM * BK / 2048; ++i) {
            int idx = tid + i * 256;
            int row = idx >> SSH, seg = idx & (SEGS - 1);
            int gseg = seg ^ ((row >> RSH) & (SEGS - 1));
            const ushort_t* g = A + aBase + (long)row * K + kt + gseg * 8;
            __builtin_amdgcn_global_load_lds(
                (const __attribute__((address_space(1))) void*)g,
                (__attribute__((address_space(3))) void*)(As + idx * 8),
                16, 0, 0);
        }
        #pragma unroll
        for (int i = 0; i < BN * BK / 2048; ++i) {
            int idx = tid + i * 256;
            int row = idx >> SSH, seg = idx & (SEGS - 1);
            int gseg = seg ^ ((row >> RSH) & (SEGS - 1));
            const ushort_t* g = B + bBase + (long)row * K + kt + gseg * 8;
            __builtin_amdgcn_global_load_lds(
                (const __attribute__((address_space(1))) void*)g,
                (__attribute__((address_space(3))) void*)(Bs + idx * 8),
                16, 0, 0);
        }
        __syncthreads();

        #pragma unroll
        for (int ks = 0; ks < BK / 32; ++ks) {
            short8 af[TM], bfr[TN];
            #pragma unroll
            for (int t = 0; t < TM; ++t) {
                int srow = wm * TM * 16 + t * 16 + l16;
                int rseg = (ks * 4 + q) ^ ((srow >> RSH) & (SEGS - 1));
                af[t] = *reinterpret_cast<const short8*>(&As[srow * BK + rseg * 8]);
            }
            #pragma unroll
            for (int t = 0; t < TN; ++t) {
                int srow = wn * TN * 16 + t * 16 + l16;
                int rseg = (ks * 4 + q) ^ ((srow >> RSH) & (SEGS - 1));
                bfr[t] = *reinterpret_cast<const short8*>(&Bs[srow * BK + rseg * 8]);
            }
            #pragma unroll
            for (int i = 0; i < TM; ++i)
                #pragma unroll
                for (int jj = 0; jj < TN; ++jj)
                    acc[i][jj] = __builtin_amdgcn_mfma_f32_16x16x32_bf16(
                        af[i], bfr[jj], acc[i][jj], 0, 0, 0);
        }
    }

    #pragma unroll
    for (int i = 0; i < TM; ++i) {
        #pragma unroll
        for (int jj = 0; jj < TN; ++jj) {
            #pragma unroll
            for (int r = 0; r < 4; ++r) {
                int row = bm * BM + wm * TM * 16 + i * 16 + q * 4 + r;
                int col = bn * BN + wn * TN * 16 + jj * 16 + l16;
                float v = acc[i][jj][r];
                if constexpr (EPI == 2) {
                    v += ep0[col];
                    v = v > 0.f ? v : 0.f;
                    Cb[(long)row * N + col] = f2bf(v);
                } else if constexpr (EPI == 3) {
                    const int half = N >> 1;
                    if (col < half)
                        Cf[(long)row * half + col] = v + ep0[col];
                    else
                        Cf[(long)M * half + (long)row * half + (col - half)] = v + ep1[col - half];
                } else {
                    Cf[(long)sk * M * N + (long)row * N + col] = v;
                }
            }
        }
    }
}

// =====================================================================
// R4: G2 as the verified m201-style 4-phase/K-tile schedule.
// BM=BN=256, BK=64, 8 waves (2M x 4N), LDS = 2 dbuf x (A 32K + B 32K) = 128 KiB.
// Per K-tile t (buf = t&1), 4 phases, each:
//   { few ds_reads (+ one half-tile DMA stage) -> barrier -> lgkmcnt(0)
//     -> sched_barrier(0) -> setprio(1) -> 16 MFMA -> setprio(0) -> barrier }
// Phase->quadrant: p0 = acc[0..3][0..1] (Alo x Blo), p1 = [0..3][2..3],
//                  p2 = [4..7][0..1],              p3 = [4..7][2..3].
// Stage placement (WAR-provable):
//   B-halves of buf[t&1] last read at p1 (bhi)  -> stage B(t+2) in p2.
//   A-halves of buf[t&1] last read at p2 (ahi)  -> stage A(t+2) in p3.
// vmcnt(8) once per K-tile at p3 end: allows t+2's 8 loads in flight,
// forces t+1's loads (issued last iter) landed; final barrier publishes.
// Tail: t==NT-2 -> vmcnt(0); t==NT-1 -> no stage/wait.
// =====================================================================
__global__ __launch_bounds__(512, 2) void g2_256(const ushort_t* __restrict__ A,
        const ushort_t* __restrict__ B, ushort_t* __restrict__ Cb,
        const float* __restrict__ bias, int M, int N, int K) {
    constexpr int BM = 256, BN = 256, BK = 64;
    __shared__ __align__(16) ushort_t As[2][BM * BK];   // 2 x 32 KiB
    __shared__ __align__(16) ushort_t Bs[2][BN * BK];   // 2 x 32 KiB

    const int tid  = threadIdx.x;       // 0..511
    const int lane = tid & 63;
    const int wave = tid >> 6;          // 0..7
    const int wm   = wave >> 2;         // 0..1  (M half: 128 rows)
    const int wn   = wave & 3;          // 0..3  (N quarter: 64 cols)
    const int q    = lane >> 4;
    const int l16  = lane & 15;

    const int tilesM = M / BM;          // 64
    const int tilesN = N / BN;          // 4
    int bid = (int)blockIdx.x;
    const int xcd = bid & 7;
    const int jb  = bid >> 3;
    const int bm  = xcd * (tilesM >> 3) + jb / tilesN;
    const int bn  = jb % tilesN;
    const int NT  = K / BK;             // 32

    const long aBase = (long)bm * BM * K;
    const long bBase = (long)bn * BN * K;

    floatx4 acc[8][4];
    #pragma unroll
    for (int i = 0; i < 8; ++i)
        #pragma unroll
        for (int j = 0; j < 4; ++j)
            acc[i][j] = (floatx4){0.f, 0.f, 0.f, 0.f};

    // stage one 128-row half (16 KiB) of A or B for tile tt.
    // linear LDS dest (idx*16B), swizzle encoded in the GLOBAL source (rule #21).
#define STG_A(h, tt) do {                                                           \
        _Pragma("unroll")                                                           \
        for (int _g = 0; _g < 2; ++_g) {                                            \
            int _idx = _g * 512 + tid;                                              \
            int _r = _idx >> 3, _s = _idx & 7;                                      \
            int _gs = _s ^ (_r & 7);                                                \
            const ushort_t* _gp = A + aBase + (long)((h) * 128 + _r) * K            \
                                  + (tt) * BK + _gs * 8;                            \
            __builtin_amdgcn_global_load_lds(                                       \
                (const __attribute__((address_space(1))) void*)_gp,                 \
                (__attribute__((address_space(3))) void*)                           \
                    (&As[(tt) & 1][(h) * 8192 + _idx * 8]),                         \
                16, 0, 0);                                                          \
        } } while (0)
#define STG_B(h, tt) do {                                                           \
        _Pragma("unroll")                                                           \
        for (int _g = 0; _g < 2; ++_g) {                                            \
            int _idx = _g * 512 + tid;                                              \
            int _r = _idx >> 3, _s = _idx & 7;                                      \
            int _gs = _s ^ (_r & 7);                                                \
            const ushort_t* _gp = B + bBase + (long)((h) * 128 + _r) * K            \
                                  + (tt) * BK + _gs * 8;                            \
            __builtin_amdgcn_global_load_lds(                                       \
                (const __attribute__((address_space(1))) void*)_gp,                 \
                (__attribute__((address_space(3))) void*)                           \
                    (&Bs[(tt) & 1][(h) * 8192 + _idx * 8]),                         \
                16, 0, 0);                                                          \
        } } while (0)

    // fragment reads: 4 M-frags (RDA) / 2 N-frags (RDB) x 2 K-steps
#define RDA(dst, IB) do {                                                           \
        _Pragma("unroll")                                                           \
        for (int _i = 0; _i < 4; ++_i)                                              \
            _Pragma("unroll")                                                       \
            for (int _k = 0; _k < 2; ++_k) {                                        \
                int _sr = wm * 128 + ((IB) + _i) * 16 + l16;                        \
                int _rs = (_k * 4 + q) ^ (_sr & 7);                                 \
                dst[_i][_k] = *reinterpret_cast<const short8*>(                     \
                    &As[_buf][_sr * BK + _rs * 8]);                                 \
            } } while (0)
#define RDB(dst, JB) do {                                                           \
        _Pragma("unroll")                                                           \
        for (int _j = 0; _j < 2; ++_j)                                              \
            _Pragma("unroll")                                                       \
            for (int _k = 0; _k < 2; ++_k) {                                        \
                int _sr = wn * 64 + ((JB) + _j) * 16 + l16;                         \
                int _rs = (_k * 4 + q) ^ (_sr & 7);                                 \
                dst[_j][_k] = *reinterpret_cast<const short8*>(                     \
                    &Bs[_buf][_sr * BK + _rs * 8]);                                 \
            } } while (0)

#define MM(AF, BF, IB, JB) do {                                                     \
        __builtin_amdgcn_s_setprio(1);                                              \
        _Pragma("unroll")                                                           \
        for (int _k = 0; _k < 2; ++_k)                                              \
            _Pragma("unroll")                                                       \
            for (int _i = 0; _i < 4; ++_i)                                          \
                _Pragma("unroll")                                                   \
                for (int _j = 0; _j < 2; ++_j)                                      \
                    acc[(IB) + _i][(JB) + _j] =                                     \
                        __builtin_amdgcn_mfma_f32_16x16x32_bf16(                    \
                            AF[_i][_k], BF[_j][_k],                                 \
                            acc[(IB) + _i][(JB) + _j], 0, 0, 0);                    \
        __builtin_amdgcn_s_setprio(0);                                              \
    } while (0)

#define MID do { __builtin_amdgcn_s_barrier();                                      \
        asm volatile("s_waitcnt lgkmcnt(0)" ::: "memory");                          \
        __builtin_amdgcn_sched_barrier(0); } while (0)
#define ENDP do { __builtin_amdgcn_s_barrier();                                     \
        asm volatile("" ::: "memory"); } while (0)

    // prologue: stage tiles 0 and 1 fully; tile 0 landed; publish
    STG_A(0, 0); STG_A(1, 0); STG_B(0, 0); STG_B(1, 0);
    STG_A(0, 1); STG_A(1, 1); STG_B(0, 1); STG_B(1, 1);
    asm volatile("s_waitcnt vmcnt(8)" ::: "memory");
    __builtin_amdgcn_s_barrier();
    asm volatile("" ::: "memory");

    short8 alo[4][2], ahi[4][2], blo[2][2], bhi[2][2];

    for (int t = 0; t < NT; ++t) {
        const int _buf = t & 1;
        // ---- p0: read Alo+Blo; MFMA q0 ----
        RDA(alo, 0);
        RDB(blo, 0);
        MID;
        MM(alo, blo, 0, 0);
        ENDP;
        // ---- p1: read Bhi; MFMA q1 ----
        RDB(bhi, 2);
        MID;
        MM(alo, bhi, 0, 2);
        ENDP;
        // ---- p2: read Ahi; stage B halves of t+2; MFMA q2 ----
        RDA(ahi, 4);
        if (t < NT - 2) { STG_B(0, t + 2); STG_B(1, t + 2); }
        MID;
        MM(ahi, blo, 4, 0);
        ENDP;
        // ---- p3: stage A halves of t+2; MFMA q3; counted vmcnt ----
        if (t < NT - 2) { STG_A(0, t + 2); STG_A(1, t + 2); }
        __builtin_amdgcn_s_barrier();
        asm volatile("" ::: "memory");
        MM(ahi, bhi, 4, 2);
        if (t < NT - 2)
            asm volatile("s_waitcnt vmcnt(8)" ::: "memory");
        else if (t == NT - 2)
            asm volatile("s_waitcnt vmcnt(0)" ::: "memory");
        ENDP;
    }

#undef ENDP
#undef MID
#undef MM
#undef RDB
#undef RDA
#undef STG_B
#undef STG_A

    // epilogue: bias + relu -> bf16
    float bsv[4];
    #pragma unroll
    for (int j = 0; j < 4; ++j)
        bsv[j] = bias[bn * BN + wn * 64 + j * 16 + l16];
    #pragma unroll
    for (int i = 0; i < 8; ++i) {
        int row = bm * BM + wm * 128 + i * 16 + q * 4;
        #pragma unroll
        for (int j = 0; j < 4; ++j) {
            int col = bn * BN + wn * 64 + j * 16 + l16;
            #pragma unroll
            for (int r = 0; r < 4; ++r) {
                float v = acc[i][j][r] + bsv[j];
                v = v > 0.f ? v : 0.f;
                Cb[(long)(row + r) * N + col] = f2bf(v);
            }
        }
    }
}

// ---- 128x128 tile pipelined core: 256 thr (4 waves 2x2), BK=32, ring-4 (64 KiB) ----
// EPI 2: +bias,relu->bf16 | 3: +bias split fp32 (mu|logvar)
template<int EPI>
__device__ __forceinline__ void gemm128_v2(
        const ushort_t* __restrict__ A, const ushort_t* __restrict__ B,
        ushort_t* __restrict__ Cb, float* __restrict__ Cf,
        const float* __restrict__ ep0, const float* __restrict__ ep1,
        int M, int N, int K) {
    constexpr int BM = 128, BN = 128, BK = 32;
    __shared__ __align__(16) ushort_t As[4][BM * BK];   // 4 x 8 KiB
    __shared__ __align__(16) ushort_t Bs[4][BN * BK];   // 4 x 8 KiB

    const int tid  = threadIdx.x;
    const int lane = tid & 63;
    const int wave = tid >> 6;
    const int wm   = wave >> 1;
    const int wn   = wave & 1;
    const int q    = lane >> 4;
    const int l16  = lane & 15;

    const int tilesM = M / BM;
    const int tilesN = N / BN;
    int bid = (int)blockIdx.x;
    const int xcd = bid & 7;
    const int jb  = bid >> 3;
    const int bm  = xcd * (tilesM >> 3) + jb / tilesN;
    const int bn  = jb % tilesN;
    const int NT  = K / BK;

    const long aBase = (long)bm * BM * K;
    const long bBase = (long)bn * BN * K;

    floatx4 acc[4][4];
    #pragma unroll
    for (int i = 0; i < 4; ++i)
        #pragma unroll
        for (int j = 0; j < 4; ++j)
            acc[i][j] = (floatx4){0.f, 0.f, 0.f, 0.f};

#define STAGE_A(t) do { int _sl = (t) & 3;                                          \
        _Pragma("unroll")                                                           \
        for (int _g = 0; _g < 2; ++_g) {                                            \
            int _idx = _g * 256 + tid;                                              \
            int _row = _idx >> 2, _seg = _idx & 3;                                  \
            int _gs = _seg ^ ((_row >> 1) & 3);                                     \
            const ushort_t* _gp = A + aBase + (long)_row * K + (t) * BK + _gs * 8;  \
            __builtin_amdgcn_global_load_lds(                                       \
                (const __attribute__((address_space(1))) void*)_gp,                 \
                (__attribute__((address_space(3))) void*)(&As[_sl][_idx * 8]),      \
                16, 0, 0);                                                          \
        } } while (0)
#define STAGE_B(t) do { int _sl = (t) & 3;                                          \
        _Pragma("unroll")                                                           \
        for (int _g = 0; _g < 2; ++_g) {                                            \
            int _idx = _g * 256 + tid;                                              \
            int _row = _idx >> 2, _seg = _idx & 3;                                  \
            int _gs = _seg ^ ((_row >> 1) & 3);                                     \
            const ushort_t* _gp = B + bBase + (long)_row * K + (t) * BK + _gs * 8;  \
            __builtin_amdgcn_global_load_lds(                                       \
                (const __attribute__((address_space(1))) void*)_gp,                 \
                (__attribute__((address_space(3))) void*)(&Bs[_sl][_idx * 8]),      \
                16, 0, 0);                                                          \
        } } while (0)

    STAGE_A(0); STAGE_B(0);
    STAGE_A(1); STAGE_B(1);
    STAGE_A(2); STAGE_B(2);
    asm volatile("s_waitcnt vmcnt(8)" ::: "memory");
    __builtin_amdgcn_s_barrier();
    asm volatile("" ::: "memory");

#define KTILE(tt, DOSTAGE, WAITOP) do {                                             \
        const int _slot = (tt) & 3;                                                 \
        short8 _bf[4], _af[4];                                                      \
        _Pragma("unroll")                                                           \
        for (int _j = 0; _j < 4; ++_j) {                                            \
            int _sr = wn * 64 + _j * 16 + l16;                                      \
            int _rs = q ^ ((_sr >> 1) & 3);                                         \
            _bf[_j] = *reinterpret_cast<const short8*>(&Bs[_slot][_sr * BK + _rs * 8]); \
        }                                                                           \
        _Pragma("unroll")                                                           \
        for (int _i = 0; _i < 4; ++_i) {                                            \
            int _sr = wm * 64 + _i * 16 + l16;                                      \
            int _rs = q ^ ((_sr >> 1) & 3);                                         \
            _af[_i] = *reinterpret_cast<const short8*>(&As[_slot][_sr * BK + _rs * 8]); \
        }                                                                           \
        if (DOSTAGE) { STAGE_A((tt) + 3); STAGE_B((tt) + 3); }                      \
        __builtin_amdgcn_s_setprio(1);                                              \
        _Pragma("unroll")                                                           \
        for (int _i = 0; _i < 4; ++_i)                                              \
            _Pragma("unroll")                                                       \
            for (int _j = 0; _j < 4; ++_j)                                          \
                acc[_i][_j] = __builtin_amdgcn_mfma_f32_16x16x32_bf16(              \
                    _af[_i], _bf[_j], acc[_i][_j], 0, 0, 0);                        \
        __builtin_amdgcn_s_setprio(0);                                              \
        asm volatile("s_waitcnt lgkmcnt(0)" ::: "memory");                          \
        __builtin_amdgcn_sched_barrier(0);                                          \
        WAITOP;                                                                     \
        __builtin_amdgcn_s_barrier();                                               \
        asm volatile("" ::: "memory");                                              \
    } while (0)

    int t = 0;
    for (; t < NT - 3; ++t) {
        KTILE(t, true, asm volatile("s_waitcnt vmcnt(8)" ::: "memory"));
    }
    KTILE(t, false, asm volatile("s_waitcnt vmcnt(4)" ::: "memory")); ++t;
    KTILE(t, false, asm volatile("s_waitcnt vmcnt(0)" ::: "memory")); ++t;
    KTILE(t, false, (void)0);

#undef KTILE
#undef STAGE_A
#undef STAGE_B

    #pragma unroll
    for (int i = 0; i < 4; ++i) {
        #pragma unroll
        for (int jj = 0; jj < 4; ++jj) {
            #pragma unroll
            for (int r = 0; r < 4; ++r) {
                int row = bm * BM + wm * 64 + i * 16 + q * 4 + r;
                int col = bn * BN + wn * 64 + jj * 16 + l16;
                float v = acc[i][jj][r];
                if constexpr (EPI == 2) {
                    v += ep0[col];
                    v = v > 0.f ? v : 0.f;
                    Cb[(long)row * N + col] = f2bf(v);
                } else {
                    const int half = N >> 1;
                    v += (col < half) ? ep0[col] : ep1[col - half];
                    if (col < half)
                        Cf[(long)row * half + col] = v;
                    else
                        Cf[(long)M * half + (long)row * half + (col - half)] = v;
                }
            }
        }
    }
}

// named wrappers (rocprof per-stage attribution)
__global__ __launch_bounds__(256) void g0p_sk(const ushort_t* A, const ushort_t* B,
        float* P, int M, int N, int K, int KC) {
    gemm_core<4, 4, 32, 4, true>(A, B, nullptr, P, nullptr, nullptr, M, N, K, KC);
}
__global__ __launch_bounds__(256) void g1p_sk(const ushort_t* A, const ushort_t* B,
        float* P, int M, int N, int K, int KC) {
    gemm_core<4, 4, 32, 4, true>(A, B, nullptr, P, nullptr, nullptr, M, N, K, KC);
}
__global__ __launch_bounds__(256, 2) void g3_h2(const ushort_t* A, const ushort_t* B,
        ushort_t* Cb, const float* ep0, int M, int N, int K) {
    gemm128_v2<2>(A, B, Cb, nullptr, ep0, nullptr, M, N, K);
}
__global__ __launch_bounds__(256, 2) void g4_head(const ushort_t* A, const ushort_t* B,
        float* Cf, const float* ep0, const float* ep1, int M, int N, int K) {
    gemm128_v2<3>(A, B, nullptr, Cf, ep0, ep1, M, N, K);
}

extern "C" void kernel_launch(void* const* d_in, const int* in_sizes, int n_in,
                              void* d_out, int out_size, void* d_ws, size_t ws_size,
                              hipStream_t stream) {
    const float* x   = (const float*)d_in[0];
    const float* fw  = (const float*)d_in[1];
    const float* kp  = (const float*)d_in[2];
    const float* W1  = (const float*)d_in[3];
    const float* b1  = (const float*)d_in[4];
    const float* W2  = (const float*)d_in[5];
    const float* b2  = (const float*)d_in[6];
    const float* Wmu = (const float*)d_in[7];
    const float* bmu = (const float*)d_in[8];
    const float* Wlv = (const float*)d_in[9];
    const float* blv = (const float*)d_in[10];
    float* out = (float*)d_out;

    char* ws = (char*)d_ws;
    const size_t MB = 1024 * 1024;
    // timeline-safe overlays (total 118.01 MB, within proven R0 footprint):
    ushort_t* W1bf = (ushort_t*)(ws + 0);         //  4 MB   dead after g0p
    ushort_t* Dbf  = (ushort_t*)(ws + 4   * MB);  //  8 MB   dead after g0p
    ushort_t* Dtbf = (ushort_t*)(ws + 12  * MB);  //  8 MB   dead after g1p
    ushort_t* T1sT = (ushort_t*)(ws + 20  * MB);  //  4 MB   dead after g1p
    ushort_t* H1   = (ushort_t*)(ws + 0);         // 32 MB   written by g2 (overlays above)
    float*    P    = (float*)   (ws + 32  * MB);  // 32 MB   dead after k_red #2
    ushort_t* Xbf  = (ushort_t*)(ws + 32  * MB);  // 64 MB   written after P dead (32..96)
    ushort_t* H2   = (ushort_t*)(ws + 96  * MB);  // 16 MB
    ushort_t* M1T  = (ushort_t*)(ws + 112 * MB);  //  4 MB
    ushort_t* W2bf = (ushort_t*)(ws + 116 * MB);  //  1 MB
    ushort_t* Wcat = (ushort_t*)(ws + 117 * MB);  // 0.5 MB
    float*    svec = (float*)   (ws + 118 * MB);  //  8 KB

    hipLaunchKernelGGL(k_scale, dim3(DIM / 256), dim3(256), 0, stream, fw, kp, svec);
    hipLaunchKernelGGL(k_gen_d, dim3(DIM * DIM / 256), dim3(256), 0, stream, Dbf, Dtbf);
    hipLaunchKernelGGL(k_cast_w, dim3((U_W1 + U_W2 + 2 * U_WH) / 256), dim3(256), 0, stream,
                       W1, W2, Wmu, Wlv, W1bf, W2bf, Wcat);

    // G0 (split-K=4): P[sk] = W1bf @ Dbf^T chunk   (1024 x 2048, KC=512)
    hipLaunchKernelGGL(g0p_sk, dim3(8 * 16 * 4), dim3(256), 0, stream,
                       W1bf, Dbf, P, 1024, 2048, 2048, 512);
    // reduce + scale -> T1sT
    hipLaunchKernelGGL(k_red, dim3(1024 * 2048 / 4 / 256), dim3(256), 0, stream,
                       P, T1sT, svec, 1024 * 2048 / 4, 2048 / 4);
    // G1 (split-K=4): P[sk] = T1sT @ Dtbf^T chunk  (1024 x 2048, KC=512)
    hipLaunchKernelGGL(g1p_sk, dim3(8 * 16 * 4), dim3(256), 0, stream,
                       T1sT, Dtbf, P, 1024, 2048, 2048, 512);
    // reduce -> M1T
    hipLaunchKernelGGL(k_red, dim3(1024 * 2048 / 4 / 256), dim3(256), 0, stream,
                       P, M1T, nullptr, 1024 * 2048 / 4, 2048 / 4);

    // X cast (after P is dead; Xbf overlays P region)
    hipLaunchKernelGGL(k_cast_x, dim3(BATCH * DIM / 8 / 256), dim3(256), 0, stream, x, Xbf);

    // G2: H1 = relu(Xbf @ M1 + b1)   (16384 x 1024, K=2048) — 256² 4-phase BK=64
    hipLaunchKernelGGL(g2_256, dim3((BATCH / 256) * (1024 / 256)), dim3(512), 0, stream,
                       Xbf, M1T, H1, b1, BATCH, 1024, 2048);
    // G3: H2 = relu(H1 @ W2^T + b2)  (16384 x 512, K=1024) — 128² ring-4 pipelined
    hipLaunchKernelGGL(g3_h2, dim3((BATCH / 128) * (512 / 128)), dim3(256), 0, stream,
                       H1, W2bf, H2, b2, BATCH, 512, 1024);
    // G4: [mu | logvar] = H2 @ Wcat^T + bias, fp32 split (16384 x 512, K=512)
    hipLaunchKernelGGL(g4_head, dim3((BATCH / 128) * (512 / 128)), dim3(256), 0, stream,
                       H2, Wcat, out, bmu, blv, BATCH, 512, 512);

    (void)in_sizes; (void)n_in; (void)out_size; (void)ws_size;
}

// Round 5
// 379.643 us; speedup vs baseline: 1.0349x; 1.0168x over previous
//
#include <hip/hip_runtime.h>
#include <hip/hip_bf16.h>
#include <math.h>

#define DIM 2048
#define BATCH 16384

typedef __attribute__((ext_vector_type(8))) short short8;
typedef __attribute__((ext_vector_type(4))) short short4v;
typedef __attribute__((ext_vector_type(4))) float floatx4;
typedef unsigned short ushort_t;

__device__ __forceinline__ ushort_t f2bf(float f) {
    union { float f; unsigned u; } v; v.f = f;
    unsigned r = v.u + 0x7FFFu + ((v.u >> 16) & 1u);   // RNE
    return (ushort_t)(r >> 16);
}

// ---- band scale vector (length DIM) ----
__global__ void k_scale(const float* __restrict__ fw, const float* __restrict__ kp,
                        float* __restrict__ s) {
    int n = blockIdx.x * blockDim.x + threadIdx.x;
    if (n >= DIM) return;
    float kv = kp[0];
    float f = 1.0f;
    for (int i = 0; i < 30; ++i) {
        long s0 = (long)((double)i       * (double)(DIM - 1) / 30.0);
        long e0 = (long)((double)(i + 1) * (double)(DIM - 1) / 30.0);
        if (n >= s0 && n < e0) {
            if (e0 <= 30)
                f = 1.0f + fw[i] * kv * (1.0f - (float)i / 30.0f);
            else
                f = 1.0f - fw[i] * kv * (1.0f - (float)(i - 30) / 30.0f);
        }
    }
    s[n] = f;
}

// ---- DCT matrix + transpose, bf16, exact integer phase reduction ----
__global__ void k_gen_d(ushort_t* __restrict__ D, ushort_t* __restrict__ Dt) {
    int idx = blockIdx.x * blockDim.x + threadIdx.x;   // DIM*DIM
    int r = idx >> 11;
    int c = idx & (DIM - 1);
    const float w  = 7.6699039394282058e-4f;  // pi/4096
    const float s0 = 0.02209708691207961f;    // sqrt(1/2048)
    const float s1 = 0.03125f;                // sqrt(2/2048)
    int m1 = ((2 * c + 1) * r) & (4 * DIM - 1);
    int m2 = ((2 * r + 1) * c) & (4 * DIM - 1);
    float v1 = __cosf(w * (float)m1) * (r == 0 ? s0 : s1);   // arg < 2pi
    float v2 = __cosf(w * (float)m2) * (c == 0 ? s0 : s1);
    D[idx]  = f2bf(v1);
    Dt[idx] = f2bf(v2);
}

// ---- fp32 -> bf16 casts ----
#define U_W1   262144
#define U_W2    65536
#define U_WH    16384
__global__ void k_cast_w(const float* __restrict__ W1, const float* __restrict__ W2,
                         const float* __restrict__ Wmu, const float* __restrict__ Wlv,
                         ushort_t* __restrict__ W1bf, ushort_t* __restrict__ W2bf,
                         ushort_t* __restrict__ Wcat) {
    int i = blockIdx.x * blockDim.x + threadIdx.x;
    const float* src; ushort_t* dst; int u;
    if (i < U_W1)                    { src = W1;  dst = W1bf;             u = i; }
    else if (i < U_W1 + U_W2)        { src = W2;  dst = W2bf;             u = i - U_W1; }
    else if (i < U_W1 + U_W2 + U_WH) { src = Wmu; dst = Wcat;             u = i - U_W1 - U_W2; }
    else                             { src = Wlv; dst = Wcat + 8 * U_WH;  u = i - U_W1 - U_W2 - U_WH; }
    const float4* p = reinterpret_cast<const float4*>(src) + 2 * (size_t)u;
    float4 a = p[0], b = p[1];
    short8 r;
    r[0] = (short)f2bf(a.x); r[1] = (short)f2bf(a.y);
    r[2] = (short)f2bf(a.z); r[3] = (short)f2bf(a.w);
    r[4] = (short)f2bf(b.x); r[5] = (short)f2bf(b.y);
    r[6] = (short)f2bf(b.z); r[7] = (short)f2bf(b.w);
    *reinterpret_cast<short8*>(dst + 8 * (size_t)u) = r;
}

__global__ void k_cast_x(const float* __restrict__ in, ushort_t* __restrict__ out) {
    int i = blockIdx.x * blockDim.x + threadIdx.x;
    const float4* p = reinterpret_cast<const float4*>(in) + 2 * (size_t)i;
    float4 a = p[0], b = p[1];
    short8 r;
    r[0] = (short)f2bf(a.x); r[1] = (short)f2bf(a.y);
    r[2] = (short)f2bf(a.z); r[3] = (short)f2bf(a.w);
    r[4] = (short)f2bf(b.x); r[5] = (short)f2bf(b.y);
    r[6] = (short)f2bf(b.z); r[7] = (short)f2bf(b.w);
    *reinterpret_cast<short8*>(out + 8 * (size_t)i) = r;
}

// ---- split-K reduce: out = bf16( (P0+P1+P2+P3) [* scale[col]] ) ----
__global__ void k_red(const float* __restrict__ P, ushort_t* __restrict__ out,
                      const float* __restrict__ scale, int n4, int n4row) {
    int i = blockIdx.x * blockDim.x + threadIdx.x;   // float4 index
    const float4* p = reinterpret_cast<const float4*>(P);
    float4 a = p[i], b = p[i + n4], c = p[i + 2 * n4], d = p[i + 3 * n4];
    float4 s;
    s.x = a.x + b.x + c.x + d.x;
    s.y = a.y + b.y + c.y + d.y;
    s.z = a.z + b.z + c.z + d.z;
    s.w = a.w + b.w + c.w + d.w;
    if (scale) {
        float4 sc = reinterpret_cast<const float4*>(scale)[i & (n4row - 1)];
        s.x *= sc.x; s.y *= sc.y; s.z *= sc.z; s.w *= sc.w;
    }
    short4v o;
    o[0] = (short)f2bf(s.x); o[1] = (short)f2bf(s.y);
    o[2] = (short)f2bf(s.z); o[3] = (short)f2bf(s.w);
    *reinterpret_cast<short4v*>(out + 4 * (size_t)i) = o;
}

// ---- OLD GEMM core (serial stage->drain->compute), kept for split-K G0/G1 ----
template<int TM, int TN, int BK, int EPI, bool SK4>
__device__ __forceinline__ void gemm_core(
        const ushort_t* __restrict__ A, const ushort_t* __restrict__ B,
        ushort_t* __restrict__ Cb, float* __restrict__ Cf,
        const float* __restrict__ ep0, const float* __restrict__ ep1,
        int M, int N, int K, int KC) {
    constexpr int BM = 32 * TM;
    constexpr int BN = 32 * TN;
    constexpr int SEGS = BK / 8;
    constexpr int RSH  = (BK == 32) ? 1 : 0;
    constexpr int SSH  = (SEGS == 4) ? 2 : 3;
    __shared__ __align__(16) ushort_t As[BM * BK];
    __shared__ __align__(16) ushort_t Bs[BN * BK];

    const int tid  = threadIdx.x;
    const int lane = tid & 63;
    const int wave = tid >> 6;
    const int wm   = wave >> 1;
    const int wn   = wave & 1;
    const int q    = lane >> 4;
    const int l16  = lane & 15;

    const int tilesM = M / BM;
    const int tilesN = N / BN;
    int bid = (int)blockIdx.x;
    int sk = 0;
    if constexpr (SK4) { int nt = tilesM * tilesN; sk = bid / nt; bid = bid % nt; }
    const int xcd = bid & 7;
    const int j   = bid >> 3;
    const int bm  = xcd * (tilesM >> 3) + j / tilesN;
    const int bn  = j % tilesN;

    floatx4 acc[TM][TN];
    #pragma unroll
    for (int i = 0; i < TM; ++i)
        #pragma unroll
        for (int jj = 0; jj < TN; ++jj)
            acc[i][jj] = (floatx4){0.f, 0.f, 0.f, 0.f};

    const long aBase = (long)bm * BM * K + (long)sk * KC;
    const long bBase = (long)bn * BN * K + (long)sk * KC;
    const int  KLOOP = SK4 ? KC : K;

    for (int kt = 0; kt < KLOOP; kt += BK) {
        __syncthreads();
        #pragma unroll
        for (int i = 0; i < BM * BK / 2048; ++i) {
            int idx = tid + i * 256;
            int row = idx >> SSH, seg = idx & (SEGS - 1);
            int gseg = seg ^ ((row >> RSH) & (SEGS - 1));
            const ushort_t* g = A + aBase + (long)row * K + kt + gseg * 8;
            __builtin_amdgcn_global_load_lds(
                (const __attribute__((address_space(1))) void*)g,
                (__attribute__((address_space(3))) void*)(As + idx * 8),
                16, 0, 0);
        }
        #pragma unroll
        for (int i = 0; i < BN * BK / 2048; ++i) {
            int idx = tid + i * 256;
            int row = idx >> SSH, seg = idx & (SEGS - 1);
            int gseg = seg ^ ((row >> RSH) & (SEGS - 1));
            const ushort_t* g = B + bBase + (long)row * K + kt + gseg * 8;
            __builtin_amdgcn_global_load_lds(
                (const __attribute__((address_space(1))) void*)g,
                (__attribute__((address_space(3))) void*)(Bs + idx * 8),
                16, 0, 0);
        }
        __syncthreads();

        #pragma unroll
        for (int ks = 0; ks < BK / 32; ++ks) {
            short8 af[TM], bfr[TN];
            #pragma unroll
            for (int t = 0; t < TM; ++t) {
                int srow = wm * TM * 16 + t * 16 + l16;
                int rseg = (ks * 4 + q) ^ ((srow >> RSH) & (SEGS - 1));
                af[t] = *reinterpret_cast<const short8*>(&As[srow * BK + rseg * 8]);
            }
            #pragma unroll
            for (int t = 0; t < TN; ++t) {
                int srow = wn * TN * 16 + t * 16 + l16;
                int rseg = (ks * 4 + q) ^ ((srow >> RSH) & (SEGS - 1));
                bfr[t] = *reinterpret_cast<const short8*>(&Bs[srow * BK + rseg * 8]);
            }
            #pragma unroll
            for (int i = 0; i < TM; ++i)
                #pragma unroll
                for (int jj = 0; jj < TN; ++jj)
                    acc[i][jj] = __builtin_amdgcn_mfma_f32_16x16x32_bf16(
                        af[i], bfr[jj], acc[i][jj], 0, 0, 0);
        }
    }

    #pragma unroll
    for (int i = 0; i < TM; ++i) {
        #pragma unroll
        for (int jj = 0; jj < TN; ++jj) {
            #pragma unroll
            for (int r = 0; r < 4; ++r) {
                int row = bm * BM + wm * TM * 16 + i * 16 + q * 4 + r;
                int col = bn * BN + wn * TN * 16 + jj * 16 + l16;
                float v = acc[i][jj][r];
                if constexpr (EPI == 2) {
                    v += ep0[col];
                    v = v > 0.f ? v : 0.f;
                    Cb[(long)row * N + col] = f2bf(v);
                } else if constexpr (EPI == 3) {
                    const int half = N >> 1;
                    if (col < half)
                        Cf[(long)row * half + col] = v + ep0[col];
                    else
                        Cf[(long)M * half + (long)row * half + (col - half)] = v + ep1[col - half];
                } else {
                    Cf[(long)sk * M * N + (long)row * N + col] = v;
                }
            }
        }
    }
}

// =====================================================================
// R5: G2 with PHASE-LEVEL READ-AHEAD (the m196/m201 interleave lever).
// Geometry unchanged (256x256, 8 waves 2Mx4N, BK=64, 2-dbuf 128 KiB).
// Each quadrant-phase prefetches the NEXT phase's fragments BEFORE its
// MFMA cluster; no sched_barrier / no asm lgkm — compiler emits exact
// counted lgkmcnt, so prefetch reads complete on the LDS pipe while the
// matrix pipe drains the current 16-MFMA cluster.
//   q0: RD bhi(t)        ; MM(alo,blo)  ; bar
//   q1: RD ahi(t)        ; MM(alo,bhi)  ; vmcnt(0) ; bar   [t+1 landed]
//   q2: RD alo(t+1), STG_B(t+2) ; MM(ahi,blo) ; bar
//   q3: RD blo(t+1), STG_A(t+2) ; MM(ahi,bhi) ; bar
// WAR: each buffer's reads are consumed (compiler-drained) >=1 barrier
//      before its DMA overwrite (bhi@q0 -> drained pre-q1bar -> STG_B@q2;
//      ahi@q1 -> drained pre-q2bar -> STG_A@q3; alo'/blo' target nbuf).
// RAW: vmcnt(0)@q1 is exact — only tile t+1's 8 loads are in flight
//      (t+2's not yet issued); barrier publishes before q2/q3 reads.
// =====================================================================
__global__ __launch_bounds__(512, 2) void g2_256(const ushort_t* __restrict__ A,
        const ushort_t* __restrict__ B, ushort_t* __restrict__ Cb,
        const float* __restrict__ bias, int M, int N, int K) {
    constexpr int BM = 256, BN = 256, BK = 64;
    __shared__ __align__(16) ushort_t As[2][BM * BK];   // 2 x 32 KiB
    __shared__ __align__(16) ushort_t Bs[2][BN * BK];   // 2 x 32 KiB

    const int tid  = threadIdx.x;       // 0..511
    const int lane = tid & 63;
    const int wave = tid >> 6;          // 0..7
    const int wm   = wave >> 2;         // 0..1  (M half: 128 rows)
    const int wn   = wave & 3;          // 0..3  (N quarter: 64 cols)
    const int q    = lane >> 4;
    const int l16  = lane & 15;

    const int tilesM = M / BM;          // 64
    const int tilesN = N / BN;          // 4
    int bid = (int)blockIdx.x;
    const int xcd = bid & 7;
    const int jb  = bid >> 3;
    const int bm  = xcd * (tilesM >> 3) + jb / tilesN;
    const int bn  = jb % tilesN;
    const int NT  = K / BK;             // 32

    const long aBase = (long)bm * BM * K;
    const long bBase = (long)bn * BN * K;

    floatx4 acc[8][4];
    #pragma unroll
    for (int i = 0; i < 8; ++i)
        #pragma unroll
        for (int j = 0; j < 4; ++j)
            acc[i][j] = (floatx4){0.f, 0.f, 0.f, 0.f};

    // stage one 128-row half (16 KiB) of A or B for tile tt.
    // linear LDS dest, swizzle pre-applied on the GLOBAL source (rule #21).
#define STG_A(h, tt) do {                                                           \
        _Pragma("unroll")                                                           \
        for (int _g = 0; _g < 2; ++_g) {                                            \
            int _idx = _g * 512 + tid;                                              \
            int _r = _idx >> 3, _s = _idx & 7;                                      \
            int _gs = _s ^ (_r & 7);                                                \
            const ushort_t* _gp = A + aBase + (long)((h) * 128 + _r) * K            \
                                  + (tt) * BK + _gs * 8;                            \
            __builtin_amdgcn_global_load_lds(                                       \
                (const __attribute__((address_space(1))) void*)_gp,                 \
                (__attribute__((address_space(3))) void*)                           \
                    (&As[(tt) & 1][(h) * 8192 + _idx * 8]),                         \
                16, 0, 0);                                                          \
        } } while (0)
#define STG_B(h, tt) do {                                                           \
        _Pragma("unroll")                                                           \
        for (int _g = 0; _g < 2; ++_g) {                                            \
            int _idx = _g * 512 + tid;                                              \
            int _r = _idx >> 3, _s = _idx & 7;                                      \
            int _gs = _s ^ (_r & 7);                                                \
            const ushort_t* _gp = B + bBase + (long)((h) * 128 + _r) * K            \
                                  + (tt) * BK + _gs * 8;                            \
            __builtin_amdgcn_global_load_lds(                                       \
                (const __attribute__((address_space(1))) void*)_gp,                 \
                (__attribute__((address_space(3))) void*)                           \
                    (&Bs[(tt) & 1][(h) * 8192 + _idx * 8]),                         \
                16, 0, 0);                                                          \
        } } while (0)

    // fragment reads from buffer BUF: 4 M-frags (RDA) / 2 N-frags (RDB) x 2 k-steps
#define RDA(dst, IB, BUF) do {                                                      \
        _Pragma("unroll")                                                           \
        for (int _i = 0; _i < 4; ++_i)                                              \
            _Pragma("unroll")                                                       \
            for (int _k = 0; _k < 2; ++_k) {                                        \
                int _sr = wm * 128 + ((IB) + _i) * 16 + l16;                        \
                int _rs = (_k * 4 + q) ^ (_sr & 7);                                 \
                dst[_i][_k] = *reinterpret_cast<const short8*>(                     \
                    &As[(BUF)][_sr * BK + _rs * 8]);                                \
            } } while (0)
#define RDB(dst, JB, BUF) do {                                                      \
        _Pragma("unroll")                                                           \
        for (int _j = 0; _j < 2; ++_j)                                              \
            _Pragma("unroll")                                                       \
            for (int _k = 0; _k < 2; ++_k) {                                        \
                int _sr = wn * 64 + ((JB) + _j) * 16 + l16;                         \
                int _rs = (_k * 4 + q) ^ (_sr & 7);                                 \
                dst[_j][_k] = *reinterpret_cast<const short8*>(                     \
                    &Bs[(BUF)][_sr * BK + _rs * 8]);                                \
            } } while (0)

#define MM(AF, BF, IB, JB) do {                                                     \
        __builtin_amdgcn_s_setprio(1);                                              \
        _Pragma("unroll")                                                           \
        for (int _k = 0; _k < 2; ++_k)                                              \
            _Pragma("unroll")                                                       \
            for (int _i = 0; _i < 4; ++_i)                                          \
                _Pragma("unroll")                                                   \
                for (int _j = 0; _j < 2; ++_j)                                      \
                    acc[(IB) + _i][(JB) + _j] =                                     \
                        __builtin_amdgcn_mfma_f32_16x16x32_bf16(                    \
                            AF[_i][_k], BF[_j][_k],                                 \
                            acc[(IB) + _i][(JB) + _j], 0, 0, 0);                    \
        __builtin_amdgcn_s_setprio(0);                                              \
    } while (0)

#define BAR do { asm volatile("" ::: "memory");                                     \
        __builtin_amdgcn_s_barrier();                                               \
        asm volatile("" ::: "memory"); } while (0)

    short8 alo[4][2], ahi[4][2], blo[2][2], bhi[2][2];

    // prologue: stage tiles 0 and 1 fully; tile 0 landed; prime alo/blo(0)
    STG_A(0, 0); STG_A(1, 0); STG_B(0, 0); STG_B(1, 0);
    STG_A(0, 1); STG_A(1, 1); STG_B(0, 1); STG_B(1, 1);
    asm volatile("s_waitcnt vmcnt(8)" ::: "memory");
    BAR;
    RDA(alo, 0, 0);
    RDB(blo, 0, 0);

    int t = 0;
    for (; t < NT - 2; ++t) {
        const int buf = t & 1, nbuf = buf ^ 1;
        // q0
        RDB(bhi, 2, buf);
        MM(alo, blo, 0, 0);
        BAR;
        // q1
        RDA(ahi, 4, buf);
        MM(alo, bhi, 0, 2);
        asm volatile("s_waitcnt vmcnt(0)" ::: "memory");
        BAR;
        // q2
        RDA(alo, 0, nbuf);
        STG_B(0, t + 2); STG_B(1, t + 2);
        MM(ahi, blo, 4, 0);
        BAR;
        // q3
        RDB(blo, 0, nbuf);
        STG_A(0, t + 2); STG_A(1, t + 2);
        MM(ahi, bhi, 4, 2);
        BAR;
    }
    // t == NT-2: no staging (t+2 == NT); still need vmcnt(0) for tile NT-1
    {
        const int buf = t & 1, nbuf = buf ^ 1;
        RDB(bhi, 2, buf);
        MM(alo, blo, 0, 0);
        BAR;
        RDA(ahi, 4, buf);
        MM(alo, bhi, 0, 2);
        asm volatile("s_waitcnt vmcnt(0)" ::: "memory");
        BAR;
        RDA(alo, 0, nbuf);
        MM(ahi, blo, 4, 0);
        BAR;
        RDB(blo, 0, nbuf);
        MM(ahi, bhi, 4, 2);
        BAR;
    }
    // t == NT-1: last tile, no prefetch, no barriers needed after
    {
        const int buf = (NT - 1) & 1;
        RDB(bhi, 2, buf);
        MM(alo, blo, 0, 0);
        RDA(ahi, 4, buf);
        MM(alo, bhi, 0, 2);
        MM(ahi, blo, 4, 0);
        MM(ahi, bhi, 4, 2);
    }

#undef BAR
#undef MM
#undef RDB
#undef RDA
#undef STG_B
#undef STG_A

    // epilogue: bias + relu -> bf16
    float bsv[4];
    #pragma unroll
    for (int j = 0; j < 4; ++j)
        bsv[j] = bias[bn * BN + wn * 64 + j * 16 + l16];
    #pragma unroll
    for (int i = 0; i < 8; ++i) {
        int row = bm * BM + wm * 128 + i * 16 + q * 4;
        #pragma unroll
        for (int j = 0; j < 4; ++j) {
            int col = bn * BN + wn * 64 + j * 16 + l16;
            #pragma unroll
            for (int r = 0; r < 4; ++r) {
                float v = acc[i][j][r] + bsv[j];
                v = v > 0.f ? v : 0.f;
                Cb[(long)(row + r) * N + col] = f2bf(v);
            }
        }
    }
}

// ---- 128x128 tile pipelined core: 256 thr (4 waves 2x2), BK=32, ring-4 (64 KiB) ----
// EPI 2: +bias,relu->bf16 | 3: +bias split fp32 (mu|logvar)
template<int EPI>
__device__ __forceinline__ void gemm128_v2(
        const ushort_t* __restrict__ A, const ushort_t* __restrict__ B,
        ushort_t* __restrict__ Cb, float* __restrict__ Cf,
        const float* __restrict__ ep0, const float* __restrict__ ep1,
        int M, int N, int K) {
    constexpr int BM = 128, BN = 128, BK = 32;
    __shared__ __align__(16) ushort_t As[4][BM * BK];   // 4 x 8 KiB
    __shared__ __align__(16) ushort_t Bs[4][BN * BK];   // 4 x 8 KiB

    const int tid  = threadIdx.x;
    const int lane = tid & 63;
    const int wave = tid >> 6;
    const int wm   = wave >> 1;
    const int wn   = wave & 1;
    const int q    = lane >> 4;
    const int l16  = lane & 15;

    const int tilesM = M / BM;
    const int tilesN = N / BN;
    int bid = (int)blockIdx.x;
    const int xcd = bid & 7;
    const int jb  = bid >> 3;
    const int bm  = xcd * (tilesM >> 3) + jb / tilesN;
    const int bn  = jb % tilesN;
    const int NT  = K / BK;

    const long aBase = (long)bm * BM * K;
    const long bBase = (long)bn * BN * K;

    floatx4 acc[4][4];
    #pragma unroll
    for (int i = 0; i < 4; ++i)
        #pragma unroll
        for (int j = 0; j < 4; ++j)
            acc[i][j] = (floatx4){0.f, 0.f, 0.f, 0.f};

#define STAGE_A(t) do { int _sl = (t) & 3;                                          \
        _Pragma("unroll")                                                           \
        for (int _g = 0; _g < 2; ++_g) {                                            \
            int _idx = _g * 256 + tid;                                              \
            int _row = _idx >> 2, _seg = _idx & 3;                                  \
            int _gs = _seg ^ ((_row >> 1) & 3);                                     \
            const ushort_t* _gp = A + aBase + (long)_row * K + (t) * BK + _gs * 8;  \
            __builtin_amdgcn_global_load_lds(                                       \
                (const __attribute__((address_space(1))) void*)_gp,                 \
                (__attribute__((address_space(3))) void*)(&As[_sl][_idx * 8]),      \
                16, 0, 0);                                                          \
        } } while (0)
#define STAGE_B(t) do { int _sl = (t) & 3;                                          \
        _Pragma("unroll")                                                           \
        for (int _g = 0; _g < 2; ++_g) {                                            \
            int _idx = _g * 256 + tid;                                              \
            int _row = _idx >> 2, _seg = _idx & 3;                                  \
            int _gs = _seg ^ ((_row >> 1) & 3);                                     \
            const ushort_t* _gp = B + bBase + (long)_row * K + (t) * BK + _gs * 8;  \
            __builtin_amdgcn_global_load_lds(                                       \
                (const __attribute__((address_space(1))) void*)_gp,                 \
                (__attribute__((address_space(3))) void*)(&Bs[_sl][_idx * 8]),      \
                16, 0, 0);                                                          \
        } } while (0)

    STAGE_A(0); STAGE_B(0);
    STAGE_A(1); STAGE_B(1);
    STAGE_A(2); STAGE_B(2);
    asm volatile("s_waitcnt vmcnt(8)" ::: "memory");
    __builtin_amdgcn_s_barrier();
    asm volatile("" ::: "memory");

#define KTILE(tt, DOSTAGE, WAITOP) do {                                             \
        const int _slot = (tt) & 3;                                                 \
        short8 _bf[4], _af[4];                                                      \
        _Pragma("unroll")                                                           \
        for (int _j = 0; _j < 4; ++_j) {                                            \
            int _sr = wn * 64 + _j * 16 + l16;                                      \
            int _rs = q ^ ((_sr >> 1) & 3);                                         \
            _bf[_j] = *reinterpret_cast<const short8*>(&Bs[_slot][_sr * BK + _rs * 8]); \
        }                                                                           \
        _Pragma("unroll")                                                           \
        for (int _i = 0; _i < 4; ++_i) {                                            \
            int _sr = wm * 64 + _i * 16 + l16;                                      \
            int _rs = q ^ ((_sr >> 1) & 3);                                         \
            _af[_i] = *reinterpret_cast<const short8*>(&As[_slot][_sr * BK + _rs * 8]); \
        }                                                                           \
        if (DOSTAGE) { STAGE_A((tt) + 3); STAGE_B((tt) + 3); }                      \
        __builtin_amdgcn_s_setprio(1);                                              \
        _Pragma("unroll")                                                           \
        for (int _i = 0; _i < 4; ++_i)                                              \
            _Pragma("unroll")                                                       \
            for (int _j = 0; _j < 4; ++_j)                                          \
                acc[_i][_j] = __builtin_amdgcn_mfma_f32_16x16x32_bf16(              \
                    _af[_i], _bf[_j], acc[_i][_j], 0, 0, 0);                        \
        __builtin_amdgcn_s_setprio(0);                                              \
        asm volatile("s_waitcnt lgkmcnt(0)" ::: "memory");                          \
        __builtin_amdgcn_sched_barrier(0);                                          \
        WAITOP;                                                                     \
        __builtin_amdgcn_s_barrier();                                               \
        asm volatile("" ::: "memory");                                              \
    } while (0)

    int t = 0;
    for (; t < NT - 3; ++t) {
        KTILE(t, true, asm volatile("s_waitcnt vmcnt(8)" ::: "memory"));
    }
    KTILE(t, false, asm volatile("s_waitcnt vmcnt(4)" ::: "memory")); ++t;
    KTILE(t, false, asm volatile("s_waitcnt vmcnt(0)" ::: "memory")); ++t;
    KTILE(t, false, (void)0);

#undef KTILE
#undef STAGE_A
#undef STAGE_B

    #pragma unroll
    for (int i = 0; i < 4; ++i) {
        #pragma unroll
        for (int jj = 0; jj < 4; ++jj) {
            #pragma unroll
            for (int r = 0; r < 4; ++r) {
                int row = bm * BM + wm * 64 + i * 16 + q * 4 + r;
                int col = bn * BN + wn * 64 + jj * 16 + l16;
                float v = acc[i][jj][r];
                if constexpr (EPI == 2) {
                    v += ep0[col];
                    v = v > 0.f ? v : 0.f;
                    Cb[(long)row * N + col] = f2bf(v);
                } else {
                    const int half = N >> 1;
                    v += (col < half) ? ep0[col] : ep1[col - half];
                    if (col < half)
                        Cf[(long)row * half + col] = v;
                    else
                        Cf[(long)M * half + (long)row * half + (col - half)] = v;
                }
            }
        }
    }
}

// named wrappers (rocprof per-stage attribution)
__global__ __launch_bounds__(256) void g0p_sk(const ushort_t* A, const ushort_t* B,
        float* P, int M, int N, int K, int KC) {
    gemm_core<4, 4, 32, 4, true>(A, B, nullptr, P, nullptr, nullptr, M, N, K, KC);
}
__global__ __launch_bounds__(256) void g1p_sk(const ushort_t* A, const ushort_t* B,
        float* P, int M, int N, int K, int KC) {
    gemm_core<4, 4, 32, 4, true>(A, B, nullptr, P, nullptr, nullptr, M, N, K, KC);
}
__global__ __launch_bounds__(256, 2) void g3_h2(const ushort_t* A, const ushort_t* B,
        ushort_t* Cb, const float* ep0, int M, int N, int K) {
    gemm128_v2<2>(A, B, Cb, nullptr, ep0, nullptr, M, N, K);
}
__global__ __launch_bounds__(256, 2) void g4_head(const ushort_t* A, const ushort_t* B,
        float* Cf, const float* ep0, const float* ep1, int M, int N, int K) {
    gemm128_v2<3>(A, B, nullptr, Cf, ep0, ep1, M, N, K);
}

extern "C" void kernel_launch(void* const* d_in, const int* in_sizes, int n_in,
                              void* d_out, int out_size, void* d_ws, size_t ws_size,
                              hipStream_t stream) {
    const float* x   = (const float*)d_in[0];
    const float* fw  = (const float*)d_in[1];
    const float* kp  = (const float*)d_in[2];
    const float* W1  = (const float*)d_in[3];
    const float* b1  = (const float*)d_in[4];
    const float* W2  = (const float*)d_in[5];
    const float* b2  = (const float*)d_in[6];
    const float* Wmu = (const float*)d_in[7];
    const float* bmu = (const float*)d_in[8];
    const float* Wlv = (const float*)d_in[9];
    const float* blv = (const float*)d_in[10];
    float* out = (float*)d_out;

    char* ws = (char*)d_ws;
    const size_t MB = 1024 * 1024;
    // timeline-safe overlays (total 118.01 MB, within proven R0 footprint):
    ushort_t* W1bf = (ushort_t*)(ws + 0);         //  4 MB   dead after g0p
    ushort_t* Dbf  = (ushort_t*)(ws + 4   * MB);  //  8 MB   dead after g0p
    ushort_t* Dtbf = (ushort_t*)(ws + 12  * MB);  //  8 MB   dead after g1p
    ushort_t* T1sT = (ushort_t*)(ws + 20  * MB);  //  4 MB   dead after g1p
    ushort_t* H1   = (ushort_t*)(ws + 0);         // 32 MB   written by g2 (overlays above)
    float*    P    = (float*)   (ws + 32  * MB);  // 32 MB   dead after k_red #2
    ushort_t* Xbf  = (ushort_t*)(ws + 32  * MB);  // 64 MB   written after P dead (32..96)
    ushort_t* H2   = (ushort_t*)(ws + 96  * MB);  // 16 MB
    ushort_t* M1T  = (ushort_t*)(ws + 112 * MB);  //  4 MB
    ushort_t* W2bf = (ushort_t*)(ws + 116 * MB);  //  1 MB
    ushort_t* Wcat = (ushort_t*)(ws + 117 * MB);  // 0.5 MB
    float*    svec = (float*)   (ws + 118 * MB);  //  8 KB

    hipLaunchKernelGGL(k_scale, dim3(DIM / 256), dim3(256), 0, stream, fw, kp, svec);
    hipLaunchKernelGGL(k_gen_d, dim3(DIM * DIM / 256), dim3(256), 0, stream, Dbf, Dtbf);
    hipLaunchKernelGGL(k_cast_w, dim3((U_W1 + U_W2 + 2 * U_WH) / 256), dim3(256), 0, stream,
                       W1, W2, Wmu, Wlv, W1bf, W2bf, Wcat);

    // G0 (split-K=4): P[sk] = W1bf @ Dbf^T chunk   (1024 x 2048, KC=512)
    hipLaunchKernelGGL(g0p_sk, dim3(8 * 16 * 4), dim3(256), 0, stream,
                       W1bf, Dbf, P, 1024, 2048, 2048, 512);
    // reduce + scale -> T1sT
    hipLaunchKernelGGL(k_red, dim3(1024 * 2048 / 4 / 256), dim3(256), 0, stream,
                       P, T1sT, svec, 1024 * 2048 / 4, 2048 / 4);
    // G1 (split-K=4): P[sk] = T1sT @ Dtbf^T chunk  (1024 x 2048, KC=512)
    hipLaunchKernelGGL(g1p_sk, dim3(8 * 16 * 4), dim3(256), 0, stream,
                       T1sT, Dtbf, P, 1024, 2048, 2048, 512);
    // reduce -> M1T
    hipLaunchKernelGGL(k_red, dim3(1024 * 2048 / 4 / 256), dim3(256), 0, stream,
                       P, M1T, nullptr, 1024 * 2048 / 4, 2048 / 4);

    // X cast (after P is dead; Xbf overlays P region)
    hipLaunchKernelGGL(k_cast_x, dim3(BATCH * DIM / 8 / 256), dim3(256), 0, stream, x, Xbf);

    // G2: H1 = relu(Xbf @ M1 + b1)   (16384 x 1024, K=2048) — 256² read-ahead phases
    hipLaunchKernelGGL(g2_256, dim3((BATCH / 256) * (1024 / 256)), dim3(512), 0, stream,
                       Xbf, M1T, H1, b1, BATCH, 1024, 2048);
    // G3: H2 = relu(H1 @ W2^T + b2)  (16384 x 512, K=1024) — 128² ring-4 pipelined
    hipLaunchKernelGGL(g3_h2, dim3((BATCH / 128) * (512 / 128)), dim3(256), 0, stream,
                       H1, W2bf, H2, b2, BATCH, 512, 1024);
    // G4: [mu | logvar] = H2 @ Wcat^T + bias, fp32 split (16384 x 512, K=512)
    hipLaunchKernelGGL(g4_head, dim3((BATCH / 128) * (512 / 128)), dim3(256), 0, stream,
                       H2, Wcat, out, bmu, blv, BATCH, 512, 512);

    (void)in_sizes; (void)n_in; (void)out_size; (void)ws_size;
}

// Round 6
// 376.651 us; speedup vs baseline: 1.0431x; 1.0079x over previous
//
#include <hip/hip_runtime.h>
#include <hip/hip_bf16.h>
#include <math.h>

#define DIM 2048
#define BATCH 16384

typedef __attribute__((ext_vector_type(8))) short short8;
typedef __attribute__((ext_vector_type(4))) short short4v;
typedef __attribute__((ext_vector_type(4))) float floatx4;
typedef unsigned short ushort_t;

__device__ __forceinline__ ushort_t f2bf(float f) {
    union { float f; unsigned u; } v; v.f = f;
    unsigned r = v.u + 0x7FFFu + ((v.u >> 16) & 1u);   // RNE
    return (ushort_t)(r >> 16);
}

// ---- band scale vector (length DIM) ----
__global__ void k_scale(const float* __restrict__ fw, const float* __restrict__ kp,
                        float* __restrict__ s) {
    int n = blockIdx.x * blockDim.x + threadIdx.x;
    if (n >= DIM) return;
    float kv = kp[0];
    float f = 1.0f;
    for (int i = 0; i < 30; ++i) {
        long s0 = (long)((double)i       * (double)(DIM - 1) / 30.0);
        long e0 = (long)((double)(i + 1) * (double)(DIM - 1) / 30.0);
        if (n >= s0 && n < e0) {
            if (e0 <= 30)
                f = 1.0f + fw[i] * kv * (1.0f - (float)i / 30.0f);
            else
                f = 1.0f - fw[i] * kv * (1.0f - (float)(i - 30) / 30.0f);
        }
    }
    s[n] = f;
}

// ---- DCT matrix + transpose, bf16, exact integer phase reduction ----
__global__ void k_gen_d(ushort_t* __restrict__ D, ushort_t* __restrict__ Dt) {
    int idx = blockIdx.x * blockDim.x + threadIdx.x;   // DIM*DIM
    int r = idx >> 11;
    int c = idx & (DIM - 1);
    const float w  = 7.6699039394282058e-4f;  // pi/4096
    const float s0 = 0.02209708691207961f;    // sqrt(1/2048)
    const float s1 = 0.03125f;                // sqrt(2/2048)
    int m1 = ((2 * c + 1) * r) & (4 * DIM - 1);
    int m2 = ((2 * r + 1) * c) & (4 * DIM - 1);
    float v1 = __cosf(w * (float)m1) * (r == 0 ? s0 : s1);   // arg < 2pi
    float v2 = __cosf(w * (float)m2) * (c == 0 ? s0 : s1);
    D[idx]  = f2bf(v1);
    Dt[idx] = f2bf(v2);
}

// ---- fp32 -> bf16 casts (weights only; X-cast is fused into g2f) ----
#define U_W1   262144
#define U_W2    65536
#define U_WH    16384
__global__ void k_cast_w(const float* __restrict__ W1, const float* __restrict__ W2,
                         const float* __restrict__ Wmu, const float* __restrict__ Wlv,
                         ushort_t* __restrict__ W1bf, ushort_t* __restrict__ W2bf,
                         ushort_t* __restrict__ Wcat) {
    int i = blockIdx.x * blockDim.x + threadIdx.x;
    const float* src; ushort_t* dst; int u;
    if (i < U_W1)                    { src = W1;  dst = W1bf;             u = i; }
    else if (i < U_W1 + U_W2)        { src = W2;  dst = W2bf;             u = i - U_W1; }
    else if (i < U_W1 + U_W2 + U_WH) { src = Wmu; dst = Wcat;             u = i - U_W1 - U_W2; }
    else                             { src = Wlv; dst = Wcat + 8 * U_WH;  u = i - U_W1 - U_W2 - U_WH; }
    const float4* p = reinterpret_cast<const float4*>(src) + 2 * (size_t)u;
    float4 a = p[0], b = p[1];
    short8 r;
    r[0] = (short)f2bf(a.x); r[1] = (short)f2bf(a.y);
    r[2] = (short)f2bf(a.z); r[3] = (short)f2bf(a.w);
    r[4] = (short)f2bf(b.x); r[5] = (short)f2bf(b.y);
    r[6] = (short)f2bf(b.z); r[7] = (short)f2bf(b.w);
    *reinterpret_cast<short8*>(dst + 8 * (size_t)u) = r;
}

// ---- split-K reduce: out = bf16( (P0+P1+P2+P3) [* scale[col]] ) ----
__global__ void k_red(const float* __restrict__ P, ushort_t* __restrict__ out,
                      const float* __restrict__ scale, int n4, int n4row) {
    int i = blockIdx.x * blockDim.x + threadIdx.x;   // float4 index
    const float4* p = reinterpret_cast<const float4*>(P);
    float4 a = p[i], b = p[i + n4], c = p[i + 2 * n4], d = p[i + 3 * n4];
    float4 s;
    s.x = a.x + b.x + c.x + d.x;
    s.y = a.y + b.y + c.y + d.y;
    s.z = a.z + b.z + c.z + d.z;
    s.w = a.w + b.w + c.w + d.w;
    if (scale) {
        float4 sc = reinterpret_cast<const float4*>(scale)[i & (n4row - 1)];
        s.x *= sc.x; s.y *= sc.y; s.z *= sc.z; s.w *= sc.w;
    }
    short4v o;
    o[0] = (short)f2bf(s.x); o[1] = (short)f2bf(s.y);
    o[2] = (short)f2bf(s.z); o[3] = (short)f2bf(s.w);
    *reinterpret_cast<short4v*>(out + 4 * (size_t)i) = o;
}

// ---- OLD GEMM core (serial stage->drain->compute), kept for split-K G0/G1 ----
template<int TM, int TN, int BK, int EPI, bool SK4>
__device__ __forceinline__ void gemm_core(
        const ushort_t* __restrict__ A, const ushort_t* __restrict__ B,
        ushort_t* __restrict__ Cb, float* __restrict__ Cf,
        const float* __restrict__ ep0, const float* __restrict__ ep1,
        int M, int N, int K, int KC) {
    constexpr int BM = 32 * TM;
    constexpr int BN = 32 * TN;
    constexpr int SEGS = BK / 8;
    constexpr int RSH  = (BK == 32) ? 1 : 0;
    constexpr int SSH  = (SEGS == 4) ? 2 : 3;
    __shared__ __align__(16) ushort_t As[BM * BK];
    __shared__ __align__(16) ushort_t Bs[BN * BK];

    const int tid  = threadIdx.x;
    const int lane = tid & 63;
    const int wave = tid >> 6;
    const int wm   = wave >> 1;
    const int wn   = wave & 1;
    const int q    = lane >> 4;
    const int l16  = lane & 15;

    const int tilesM = M / BM;
    const int tilesN = N / BN;
    int bid = (int)blockIdx.x;
    int sk = 0;
    if constexpr (SK4) { int nt = tilesM * tilesN; sk = bid / nt; bid = bid % nt; }
    const int xcd = bid & 7;
    const int j   = bid >> 3;
    const int bm  = xcd * (tilesM >> 3) + j / tilesN;
    const int bn  = j % tilesN;

    floatx4 acc[TM][TN];
    #pragma unroll
    for (int i = 0; i < TM; ++i)
        #pragma unroll
        for (int jj = 0; jj < TN; ++jj)
            acc[i][jj] = (floatx4){0.f, 0.f, 0.f, 0.f};

    const long aBase = (long)bm * BM * K + (long)sk * KC;
    const long bBase = (long)bn * BN * K + (long)sk * KC;
    const int  KLOOP = SK4 ? KC : K;

    for (int kt = 0; kt < KLOOP; kt += BK) {
        __syncthreads();
        #pragma unroll
        for (int i = 0; i < BM * BK / 2048; ++i) {
            int idx = tid + i * 256;
            int row = idx >> SSH, seg = idx & (SEGS - 1);
            int gseg = seg ^ ((row >> RSH) & (SEGS - 1));
            const ushort_t* g = A + aBase + (long)row * K + kt + gseg * 8;
            __builtin_amdgcn_global_load_lds(
                (const __attribute__((address_space(1))) void*)g,
                (__attribute__((address_space(3))) void*)(As + idx * 8),
                16, 0, 0);
        }
        #pragma unroll
        for (int i = 0; i < BN * BK / 2048; ++i) {
            int idx = tid + i * 256;
            int row = idx >> SSH, seg = idx & (SEGS - 1);
            int gseg = seg ^ ((row >> RSH) & (SEGS - 1));
            const ushort_t* g = B + bBase + (long)row * K + kt + gseg * 8;
            __builtin_amdgcn_global_load_lds(
                (const __attribute__((address_space(1))) void*)g,
                (__attribute__((address_space(3))) void*)(Bs + idx * 8),
                16, 0, 0);
        }
        __syncthreads();

        #pragma unroll
        for (int ks = 0; ks < BK / 32; ++ks) {
            short8 af[TM], bfr[TN];
            #pragma unroll
            for (int t = 0; t < TM; ++t) {
                int srow = wm * TM * 16 + t * 16 + l16;
                int rseg = (ks * 4 + q) ^ ((srow >> RSH) & (SEGS - 1));
                af[t] = *reinterpret_cast<const short8*>(&As[srow * BK + rseg * 8]);
            }
            #pragma unroll
            for (int t = 0; t < TN; ++t) {
                int srow = wn * TN * 16 + t * 16 + l16;
                int rseg = (ks * 4 + q) ^ ((srow >> RSH) & (SEGS - 1));
                bfr[t] = *reinterpret_cast<const short8*>(&Bs[srow * BK + rseg * 8]);
            }
            #pragma unroll
            for (int i = 0; i < TM; ++i)
                #pragma unroll
                for (int jj = 0; jj < TN; ++jj)
                    acc[i][jj] = __builtin_amdgcn_mfma_f32_16x16x32_bf16(
                        af[i], bfr[jj], acc[i][jj], 0, 0, 0);
        }
    }

    #pragma unroll
    for (int i = 0; i < TM; ++i) {
        #pragma unroll
        for (int jj = 0; jj < TN; ++jj) {
            #pragma unroll
            for (int r = 0; r < 4; ++r) {
                int row = bm * BM + wm * TM * 16 + i * 16 + q * 4 + r;
                int col = bn * BN + wn * TN * 16 + jj * 16 + l16;
                float v = acc[i][jj][r];
                if constexpr (EPI == 2) {
                    v += ep0[col];
                    v = v > 0.f ? v : 0.f;
                    Cb[(long)row * N + col] = f2bf(v);
                } else if constexpr (EPI == 3) {
                    const int half = N >> 1;
                    if (col < half)
                        Cf[(long)row * half + col] = v + ep0[col];
                    else
                        Cf[(long)M * half + (long)row * half + (col - half)] = v + ep1[col - half];
                } else {
                    Cf[(long)sk * M * N + (long)row * N + col] = v;
                }
            }
        }
    }
}

// =====================================================================
// R6: G2 with FUSED fp32->bf16 A-cast (kills the standalone k_cast_x
// 201-MB pass). R2 ring-4 / 1-barrier structure, 256x256, BK=32, 8 waves.
// A path: global_load fp32 -> f2bf in regs -> ds_write (async split:
// loads for tile t+3 issued at iter t, converted+written at iter t+1).
// B path: all-DMA global_load_lds, distance 3, unchanged.
// Sync: the per-iter CVW's compiler-inserted COUNTED vmcnt on rA
// (in-order semantics) transitively forces all older B-DMA complete
// -> no manual vmcnt in the steady-state loop at all.
//  RAW  A(t): ds_written at iter t-2, lgkm(0)-drained before that
//             iter's barrier.
//  RAW  B(t): DMA issued iter t-3 BEFORE rA(t) loads; CVW(t) at iter
//             t-2 waits rA(t) -> B(t) landed before end-of-(t-2) bar.
//  WAR  A-slot: CVW(t+2) targets slot (t-2)&3, reads drained 2 bars ago.
//  WAR  B-slot: DMA(t+3) targets slot (t-1)&3, reads drained 1 bar ago.
// =====================================================================
__global__ __launch_bounds__(512, 2) void g2f(const float* __restrict__ Xf,
        const ushort_t* __restrict__ B, ushort_t* __restrict__ Cb,
        const float* __restrict__ bias, int M, int N, int K) {
    constexpr int BM = 256, BN = 256, BK = 32;
    __shared__ __align__(16) ushort_t As[4][BM * BK];   // 4 x 16 KiB
    __shared__ __align__(16) ushort_t Bs[4][BN * BK];   // 4 x 16 KiB

    const int tid  = threadIdx.x;       // 0..511
    const int lane = tid & 63;
    const int wave = tid >> 6;          // 0..7
    const int wm   = wave >> 2;         // 0..1  (M half: 128 rows)
    const int wn   = wave & 3;          // 0..3  (N quarter: 64 cols)
    const int q    = lane >> 4;
    const int l16  = lane & 15;

    const int tilesM = M / BM;          // 64
    const int tilesN = N / BN;          // 4
    int bid = (int)blockIdx.x;
    const int xcd = bid & 7;
    const int jb  = bid >> 3;
    const int bm  = xcd * (tilesM >> 3) + jb / tilesN;
    const int bn  = jb % tilesN;
    const int NT  = K / BK;             // 64

    const long aBase = (long)bm * BM * K;   // fp32 elements
    const long bBase = (long)bn * BN * K;   // bf16 elements

    floatx4 acc[8][4];
    #pragma unroll
    for (int i = 0; i < 8; ++i)
        #pragma unroll
        for (int j = 0; j < 4; ++j)
            acc[i][j] = (floatx4){0.f, 0.f, 0.f, 0.f};

    float4 rA[4];   // fp32 staging regs: 2 idx-groups x 8 floats

    // issue 4 global_load_dwordx4 (fp32) for A-tile tt into rA
#define LDA(tt) do {                                                                \
        _Pragma("unroll")                                                           \
        for (int _g = 0; _g < 2; ++_g) {                                            \
            int _idx = _g * 512 + tid;                                              \
            int _row = _idx >> 2, _seg = _idx & 3;                                  \
            int _gs = _seg ^ ((_row >> 1) & 3);                                     \
            const float4* _p = reinterpret_cast<const float4*>(                     \
                Xf + aBase + (long)_row * K + (tt) * BK + _gs * 8);                 \
            rA[2 * _g]     = _p[0];                                                 \
            rA[2 * _g + 1] = _p[1];                                                 \
        } } while (0)

    // convert rA -> bf16, ds_write into As slot (tt&3) (linear layout,
    // swizzle already applied on the global side in LDA)
#define CVW(tt) do { const int _sl = (tt) & 3;                                      \
        _Pragma("unroll")                                                           \
        for (int _g = 0; _g < 2; ++_g) {                                            \
            int _idx = _g * 512 + tid;                                              \
            float4 _a = rA[2 * _g], _b = rA[2 * _g + 1];                            \
            short8 _o;                                                              \
            _o[0] = (short)f2bf(_a.x); _o[1] = (short)f2bf(_a.y);                   \
            _o[2] = (short)f2bf(_a.z); _o[3] = (short)f2bf(_a.w);                   \
            _o[4] = (short)f2bf(_b.x); _o[5] = (short)f2bf(_b.y);                   \
            _o[6] = (short)f2bf(_b.z); _o[7] = (short)f2bf(_b.w);                   \
            *reinterpret_cast<short8*>(&As[_sl][_idx * 8]) = _o;                    \
        } } while (0)

#define STG_B(tt) do { const int _sl = (tt) & 3;                                    \
        _Pragma("unroll")                                                           \
        for (int _g = 0; _g < 2; ++_g) {                                            \
            int _idx = _g * 512 + tid;                                              \
            int _row = _idx >> 2, _seg = _idx & 3;                                  \
            int _gs = _seg ^ ((_row >> 1) & 3);                                     \
            const ushort_t* _gp = B + bBase + (long)_row * K + (tt) * BK + _gs * 8; \
            __builtin_amdgcn_global_load_lds(                                       \
                (const __attribute__((address_space(1))) void*)_gp,                 \
                (__attribute__((address_space(3))) void*)(&Bs[_sl][_idx * 8]),      \
                16, 0, 0);                                                          \
        } } while (0)

    // prologue: A(0),A(1) converted+written; B(0..2) DMA'd; rA holds A(2).
    LDA(0); CVW(0);
    LDA(1); CVW(1);
    STG_B(0); STG_B(1); STG_B(2);
    LDA(2);
    asm volatile("s_waitcnt lgkmcnt(0)" ::: "memory");     // A(0),A(1) writes drained
    asm volatile("s_waitcnt vmcnt(4)" ::: "memory");       // B(0..2) landed (rA(2) outstanding)
    __builtin_amdgcn_s_barrier();
    asm volatile("" ::: "memory");

    for (int t = 0; t < NT; ++t) {
        const int slot = t & 3;
        // convert+write A(t+2) (compiler inserts counted vmcnt for rA here,
        // transitively confirming B(t+1) landed)
        if (t + 2 < NT) CVW(t + 2);
        // 12 ds_read frags of tile t
        short8 bf[4], alo[4], ahi[4];
        #pragma unroll
        for (int j = 0; j < 4; ++j) {
            int sr = wn * 64 + j * 16 + l16;
            int rs = q ^ ((sr >> 1) & 3);
            bf[j] = *reinterpret_cast<const short8*>(&Bs[slot][sr * BK + rs * 8]);
        }
        #pragma unroll
        for (int i = 0; i < 4; ++i) {
            int sr = wm * 128 + i * 16 + l16;
            int rs = q ^ ((sr >> 1) & 3);
            alo[i] = *reinterpret_cast<const short8*>(&As[slot][sr * BK + rs * 8]);
        }
        #pragma unroll
        for (int i = 0; i < 4; ++i) {
            int sr = wm * 128 + 64 + i * 16 + l16;
            int rs = q ^ ((sr >> 1) & 3);
            ahi[i] = *reinterpret_cast<const short8*>(&As[slot][sr * BK + rs * 8]);
        }
        // prefetch tile t+3: B via DMA, A into regs (consumed next iter)
        if (t + 3 < NT) { STG_B(t + 3); LDA(t + 3); }
        // 32 MFMA
        __builtin_amdgcn_s_setprio(1);
        #pragma unroll
        for (int i = 0; i < 4; ++i)
            #pragma unroll
            for (int j = 0; j < 4; ++j)
                acc[i][j] = __builtin_amdgcn_mfma_f32_16x16x32_bf16(
                    alo[i], bf[j], acc[i][j], 0, 0, 0);
        #pragma unroll
        for (int i = 0; i < 4; ++i)
            #pragma unroll
            for (int j = 0; j < 4; ++j)
                acc[4 + i][j] = __builtin_amdgcn_mfma_f32_16x16x32_bf16(
                    ahi[i], bf[j], acc[4 + i][j], 0, 0, 0);
        __builtin_amdgcn_s_setprio(0);
        asm volatile("s_waitcnt lgkmcnt(0)" ::: "memory");
        __builtin_amdgcn_sched_barrier(0);
        __builtin_amdgcn_s_barrier();
        asm volatile("" ::: "memory");
    }

#undef STG_B
#undef CVW
#undef LDA

    // epilogue: bias + relu -> bf16
    float bsv[4];
    #pragma unroll
    for (int j = 0; j < 4; ++j)
        bsv[j] = bias[bn * BN + wn * 64 + j * 16 + l16];
    #pragma unroll
    for (int i = 0; i < 8; ++i) {
        int row = bm * BM + wm * 128 + i * 16 + q * 4;
        #pragma unroll
        for (int j = 0; j < 4; ++j) {
            int col = bn * BN + wn * 64 + j * 16 + l16;
            #pragma unroll
            for (int r = 0; r < 4; ++r) {
                float v = acc[i][j][r] + bsv[j];
                v = v > 0.f ? v : 0.f;
                Cb[(long)(row + r) * N + col] = f2bf(v);
            }
        }
    }
}

// ---- 128x128 tile pipelined core: 256 thr (4 waves 2x2), BK=32, ring-4 (64 KiB) ----
// EPI 2: +bias,relu->bf16 | 3: +bias split fp32 (mu|logvar)
template<int EPI>
__device__ __forceinline__ void gemm128_v2(
        const ushort_t* __restrict__ A, const ushort_t* __restrict__ B,
        ushort_t* __restrict__ Cb, float* __restrict__ Cf,
        const float* __restrict__ ep0, const float* __restrict__ ep1,
        int M, int N, int K) {
    constexpr int BM = 128, BN = 128, BK = 32;
    __shared__ __align__(16) ushort_t As[4][BM * BK];   // 4 x 8 KiB
    __shared__ __align__(16) ushort_t Bs[4][BN * BK];   // 4 x 8 KiB

    const int tid  = threadIdx.x;
    const int lane = tid & 63;
    const int wave = tid >> 6;
    const int wm   = wave >> 1;
    const int wn   = wave & 1;
    const int q    = lane >> 4;
    const int l16  = lane & 15;

    const int tilesM = M / BM;
    const int tilesN = N / BN;
    int bid = (int)blockIdx.x;
    const int xcd = bid & 7;
    const int jb  = bid >> 3;
    const int bm  = xcd * (tilesM >> 3) + jb / tilesN;
    const int bn  = jb % tilesN;
    const int NT  = K / BK;

    const long aBase = (long)bm * BM * K;
    const long bBase = (long)bn * BN * K;

    floatx4 acc[4][4];
    #pragma unroll
    for (int i = 0; i < 4; ++i)
        #pragma unroll
        for (int j = 0; j < 4; ++j)
            acc[i][j] = (floatx4){0.f, 0.f, 0.f, 0.f};

#define STAGE_A(t) do { int _sl = (t) & 3;                                          \
        _Pragma("unroll")                                                           \
        for (int _g = 0; _g < 2; ++_g) {                                            \
            int _idx = _g * 256 + tid;                                              \
            int _row = _idx >> 2, _seg = _idx & 3;                                  \
            int _gs = _seg ^ ((_row >> 1) & 3);                                     \
            const ushort_t* _gp = A + aBase + (long)_row * K + (t) * BK + _gs * 8;  \
            __builtin_amdgcn_global_load_lds(                                       \
                (const __attribute__((address_space(1))) void*)_gp,                 \
                (__attribute__((address_space(3))) void*)(&As[_sl][_idx * 8]),      \
                16, 0, 0);                                                          \
        } } while (0)
#define STAGE_B(t) do { int _sl = (t) & 3;                                          \
        _Pragma("unroll")                                                           \
        for (int _g = 0; _g < 2; ++_g) {                                            \
            int _idx = _g * 256 + tid;                                              \
            int _row = _idx >> 2, _seg = _idx & 3;                                  \
            int _gs = _seg ^ ((_row >> 1) & 3);                                     \
            const ushort_t* _gp = B + bBase + (long)_row * K + (t) * BK + _gs * 8;  \
            __builtin_amdgcn_global_load_lds(                                       \
                (const __attribute__((address_space(1))) void*)_gp,                 \
                (__attribute__((address_space(3))) void*)(&Bs[_sl][_idx * 8]),      \
                16, 0, 0);                                                          \
        } } while (0)

    STAGE_A(0); STAGE_B(0);
    STAGE_A(1); STAGE_B(1);
    STAGE_A(2); STAGE_B(2);
    asm volatile("s_waitcnt vmcnt(8)" ::: "memory");
    __builtin_amdgcn_s_barrier();
    asm volatile("" ::: "memory");

#define KTILE(tt, DOSTAGE, WAITOP) do {                                             \
        const int _slot = (tt) & 3;                                                 \
        short8 _bf[4], _af[4];                                                      \
        _Pragma("unroll")                                                           \
        for (int _j = 0; _j < 4; ++_j) {                                            \
            int _sr = wn * 64 + _j * 16 + l16;                                      \
            int _rs = q ^ ((_sr >> 1) & 3);                                         \
            _bf[_j] = *reinterpret_cast<const short8*>(&Bs[_slot][_sr * BK + _rs * 8]); \
        }                                                                           \
        _Pragma("unroll")                                                           \
        for (int _i = 0; _i < 4; ++_i) {                                            \
            int _sr = wm * 64 + _i * 16 + l16;                                      \
            int _rs = q ^ ((_sr >> 1) & 3);                                         \
            _af[_i] = *reinterpret_cast<const short8*>(&As[_slot][_sr * BK + _rs * 8]); \
        }                                                                           \
        if (DOSTAGE) { STAGE_A((tt) + 3); STAGE_B((tt) + 3); }                      \
        __builtin_amdgcn_s_setprio(1);                                              \
        _Pragma("unroll")                                                           \
        for (int _i = 0; _i < 4; ++_i)                                              \
            _Pragma("unroll")                                                       \
            for (int _j = 0; _j < 4; ++_j)                                          \
                acc[_i][_j] = __builtin_amdgcn_mfma_f32_16x16x32_bf16(              \
                    _af[_i], _bf[_j], acc[_i][_j], 0, 0, 0);                        \
        __builtin_amdgcn_s_setprio(0);                                              \
        asm volatile("s_waitcnt lgkmcnt(0)" ::: "memory");                          \
        __builtin_amdgcn_sched_barrier(0);                                          \
        WAITOP;                                                                     \
        __builtin_amdgcn_s_barrier();                                               \
        asm volatile("" ::: "memory");                                              \
    } while (0)

    int t = 0;
    for (; t < NT - 3; ++t) {
        KTILE(t, true, asm volatile("s_waitcnt vmcnt(8)" ::: "memory"));
    }
    KTILE(t, false, asm volatile("s_waitcnt vmcnt(4)" ::: "memory")); ++t;
    KTILE(t, false, asm volatile("s_waitcnt vmcnt(0)" ::: "memory")); ++t;
    KTILE(t, false, (void)0);

#undef KTILE
#undef STAGE_A
#undef STAGE_B

    #pragma unroll
    for (int i = 0; i < 4; ++i) {
        #pragma unroll
        for (int jj = 0; jj < 4; ++jj) {
            #pragma unroll
            for (int r = 0; r < 4; ++r) {
                int row = bm * BM + wm * 64 + i * 16 + q * 4 + r;
                int col = bn * BN + wn * 64 + jj * 16 + l16;
                float v = acc[i][jj][r];
                if constexpr (EPI == 2) {
                    v += ep0[col];
                    v = v > 0.f ? v : 0.f;
                    Cb[(long)row * N + col] = f2bf(v);
                } else {
                    const int half = N >> 1;
                    v += (col < half) ? ep0[col] : ep1[col - half];
                    if (col < half)
                        Cf[(long)row * half + col] = v;
                    else
                        Cf[(long)M * half + (long)row * half + (col - half)] = v;
                }
            }
        }
    }
}

// named wrappers (rocprof per-stage attribution)
__global__ __launch_bounds__(256) void g0p_sk(const ushort_t* A, const ushort_t* B,
        float* P, int M, int N, int K, int KC) {
    gemm_core<4, 4, 32, 4, true>(A, B, nullptr, P, nullptr, nullptr, M, N, K, KC);
}
__global__ __launch_bounds__(256) void g1p_sk(const ushort_t* A, const ushort_t* B,
        float* P, int M, int N, int K, int KC) {
    gemm_core<4, 4, 32, 4, true>(A, B, nullptr, P, nullptr, nullptr, M, N, K, KC);
}
__global__ __launch_bounds__(256, 2) void g3_h2(const ushort_t* A, const ushort_t* B,
        ushort_t* Cb, const float* ep0, int M, int N, int K) {
    gemm128_v2<2>(A, B, Cb, nullptr, ep0, nullptr, M, N, K);
}
__global__ __launch_bounds__(256, 2) void g4_head(const ushort_t* A, const ushort_t* B,
        float* Cf, const float* ep0, const float* ep1, int M, int N, int K) {
    gemm128_v2<3>(A, B, nullptr, Cf, ep0, ep1, M, N, K);
}

extern "C" void kernel_launch(void* const* d_in, const int* in_sizes, int n_in,
                              void* d_out, int out_size, void* d_ws, size_t ws_size,
                              hipStream_t stream) {
    const float* x   = (const float*)d_in[0];
    const float* fw  = (const float*)d_in[1];
    const float* kp  = (const float*)d_in[2];
    const float* W1  = (const float*)d_in[3];
    const float* b1  = (const float*)d_in[4];
    const float* W2  = (const float*)d_in[5];
    const float* b2  = (const float*)d_in[6];
    const float* Wmu = (const float*)d_in[7];
    const float* bmu = (const float*)d_in[8];
    const float* Wlv = (const float*)d_in[9];
    const float* blv = (const float*)d_in[10];
    float* out = (float*)d_out;

    char* ws = (char*)d_ws;
    const size_t MB = 1024 * 1024;
    // timeline-safe overlays (Xbf eliminated — g2f reads x directly):
    ushort_t* W1bf = (ushort_t*)(ws + 0);         //  4 MB   dead after g0p
    ushort_t* Dbf  = (ushort_t*)(ws + 4   * MB);  //  8 MB   dead after g0p
    ushort_t* Dtbf = (ushort_t*)(ws + 12  * MB);  //  8 MB   dead after g1p
    ushort_t* T1sT = (ushort_t*)(ws + 20  * MB);  //  4 MB   dead after g1p
    ushort_t* H1   = (ushort_t*)(ws + 0);         // 32 MB   written by g2f (overlays above)
    float*    P    = (float*)   (ws + 32  * MB);  // 32 MB   dead after k_red #2
    ushort_t* H2   = (ushort_t*)(ws + 96  * MB);  // 16 MB
    ushort_t* M1T  = (ushort_t*)(ws + 112 * MB);  //  4 MB
    ushort_t* W2bf = (ushort_t*)(ws + 116 * MB);  //  1 MB
    ushort_t* Wcat = (ushort_t*)(ws + 117 * MB);  // 0.5 MB
    float*    svec = (float*)   (ws + 118 * MB);  //  8 KB

    hipLaunchKernelGGL(k_scale, dim3(DIM / 256), dim3(256), 0, stream, fw, kp, svec);
    hipLaunchKernelGGL(k_gen_d, dim3(DIM * DIM / 256), dim3(256), 0, stream, Dbf, Dtbf);
    hipLaunchKernelGGL(k_cast_w, dim3((U_W1 + U_W2 + 2 * U_WH) / 256), dim3(256), 0, stream,
                       W1, W2, Wmu, Wlv, W1bf, W2bf, Wcat);

    // G0 (split-K=4): P[sk] = W1bf @ Dbf^T chunk   (1024 x 2048, KC=512)
    hipLaunchKernelGGL(g0p_sk, dim3(8 * 16 * 4), dim3(256), 0, stream,
                       W1bf, Dbf, P, 1024, 2048, 2048, 512);
    // reduce + scale -> T1sT
    hipLaunchKernelGGL(k_red, dim3(1024 * 2048 / 4 / 256), dim3(256), 0, stream,
                       P, T1sT, svec, 1024 * 2048 / 4, 2048 / 4);
    // G1 (split-K=4): P[sk] = T1sT @ Dtbf^T chunk  (1024 x 2048, KC=512)
    hipLaunchKernelGGL(g1p_sk, dim3(8 * 16 * 4), dim3(256), 0, stream,
                       T1sT, Dtbf, P, 1024, 2048, 2048, 512);
    // reduce -> M1T
    hipLaunchKernelGGL(k_red, dim3(1024 * 2048 / 4 / 256), dim3(256), 0, stream,
                       P, M1T, nullptr, 1024 * 2048 / 4, 2048 / 4);

    // G2 (fused X-cast): H1 = relu(bf16(x) @ M1 + b1)   (16384 x 1024, K=2048)
    hipLaunchKernelGGL(g2f, dim3((BATCH / 256) * (1024 / 256)), dim3(512), 0, stream,
                       x, M1T, H1, b1, BATCH, 1024, 2048);
    // G3: H2 = relu(H1 @ W2^T + b2)  (16384 x 512, K=1024) — 128² ring-4 pipelined
    hipLaunchKernelGGL(g3_h2, dim3((BATCH / 128) * (512 / 128)), dim3(256), 0, stream,
                       H1, W2bf, H2, b2, BATCH, 512, 1024);
    // G4: [mu | logvar] = H2 @ Wcat^T + bias, fp32 split (16384 x 512, K=512)
    hipLaunchKernelGGL(g4_head, dim3((BATCH / 128) * (512 / 128)), dim3(256), 0, stream,
                       H2, Wcat, out, bmu, blv, BATCH, 512, 512);

    (void)in_sizes; (void)n_in; (void)out_size; (void)ws_size;
}

// Round 7
// 376.646 us; speedup vs baseline: 1.0431x; 1.0000x over previous
//
#include <hip/hip_runtime.h>
#include <hip/hip_bf16.h>
#include <math.h>

#define DIM 2048
#define BATCH 16384

typedef __attribute__((ext_vector_type(8))) short short8;
typedef __attribute__((ext_vector_type(4))) short short4v;
typedef __attribute__((ext_vector_type(4))) float floatx4;
typedef unsigned short ushort_t;

__device__ __forceinline__ ushort_t f2bf(float f) {
    union { float f; unsigned u; } v; v.f = f;
    unsigned r = v.u + 0x7FFFu + ((v.u >> 16) & 1u);   // RNE
    return (ushort_t)(r >> 16);
}

// ---- band scale vector (length DIM) ----
__global__ void k_scale(const float* __restrict__ fw, const float* __restrict__ kp,
                        float* __restrict__ s) {
    int n = blockIdx.x * blockDim.x + threadIdx.x;
    if (n >= DIM) return;
    float kv = kp[0];
    float f = 1.0f;
    for (int i = 0; i < 30; ++i) {
        long s0 = (long)((double)i       * (double)(DIM - 1) / 30.0);
        long e0 = (long)((double)(i + 1) * (double)(DIM - 1) / 30.0);
        if (n >= s0 && n < e0) {
            if (e0 <= 30)
                f = 1.0f + fw[i] * kv * (1.0f - (float)i / 30.0f);
            else
                f = 1.0f - fw[i] * kv * (1.0f - (float)(i - 30) / 30.0f);
        }
    }
    s[n] = f;
}

// ---- DCT matrix + transpose, bf16, exact integer phase reduction ----
__global__ void k_gen_d(ushort_t* __restrict__ D, ushort_t* __restrict__ Dt) {
    int idx = blockIdx.x * blockDim.x + threadIdx.x;   // DIM*DIM
    int r = idx >> 11;
    int c = idx & (DIM - 1);
    const float w  = 7.6699039394282058e-4f;  // pi/4096
    const float s0 = 0.02209708691207961f;    // sqrt(1/2048)
    const float s1 = 0.03125f;                // sqrt(2/2048)
    int m1 = ((2 * c + 1) * r) & (4 * DIM - 1);
    int m2 = ((2 * r + 1) * c) & (4 * DIM - 1);
    float v1 = __cosf(w * (float)m1) * (r == 0 ? s0 : s1);   // arg < 2pi
    float v2 = __cosf(w * (float)m2) * (c == 0 ? s0 : s1);
    D[idx]  = f2bf(v1);
    Dt[idx] = f2bf(v2);
}

// ---- fp32 -> bf16 casts (weights only; X-cast is fused into g2f) ----
#define U_W1   262144
#define U_W2    65536
#define U_WH    16384
__global__ void k_cast_w(const float* __restrict__ W1, const float* __restrict__ W2,
                         const float* __restrict__ Wmu, const float* __restrict__ Wlv,
                         ushort_t* __restrict__ W1bf, ushort_t* __restrict__ W2bf,
                         ushort_t* __restrict__ Wcat) {
    int i = blockIdx.x * blockDim.x + threadIdx.x;
    const float* src; ushort_t* dst; int u;
    if (i < U_W1)                    { src = W1;  dst = W1bf;             u = i; }
    else if (i < U_W1 + U_W2)        { src = W2;  dst = W2bf;             u = i - U_W1; }
    else if (i < U_W1 + U_W2 + U_WH) { src = Wmu; dst = Wcat;             u = i - U_W1 - U_W2; }
    else                             { src = Wlv; dst = Wcat + 8 * U_WH;  u = i - U_W1 - U_W2 - U_WH; }
    const float4* p = reinterpret_cast<const float4*>(src) + 2 * (size_t)u;
    float4 a = p[0], b = p[1];
    short8 r;
    r[0] = (short)f2bf(a.x); r[1] = (short)f2bf(a.y);
    r[2] = (short)f2bf(a.z); r[3] = (short)f2bf(a.w);
    r[4] = (short)f2bf(b.x); r[5] = (short)f2bf(b.y);
    r[6] = (short)f2bf(b.z); r[7] = (short)f2bf(b.w);
    *reinterpret_cast<short8*>(dst + 8 * (size_t)u) = r;
}

// ---- split-K reduce: out = bf16( (P0+P1+P2+P3) [* scale[col]] ) ----
__global__ void k_red(const float* __restrict__ P, ushort_t* __restrict__ out,
                      const float* __restrict__ scale, int n4, int n4row) {
    int i = blockIdx.x * blockDim.x + threadIdx.x;   // float4 index
    const float4* p = reinterpret_cast<const float4*>(P);
    float4 a = p[i], b = p[i + n4], c = p[i + 2 * n4], d = p[i + 3 * n4];
    float4 s;
    s.x = a.x + b.x + c.x + d.x;
    s.y = a.y + b.y + c.y + d.y;
    s.z = a.z + b.z + c.z + d.z;
    s.w = a.w + b.w + c.w + d.w;
    if (scale) {
        float4 sc = reinterpret_cast<const float4*>(scale)[i & (n4row - 1)];
        s.x *= sc.x; s.y *= sc.y; s.z *= sc.z; s.w *= sc.w;
    }
    short4v o;
    o[0] = (short)f2bf(s.x); o[1] = (short)f2bf(s.y);
    o[2] = (short)f2bf(s.z); o[3] = (short)f2bf(s.w);
    *reinterpret_cast<short4v*>(out + 4 * (size_t)i) = o;
}

// ---- OLD GEMM core (serial stage->drain->compute), kept for split-K G0/G1 ----
template<int TM, int TN, int BK, int EPI, bool SK4>
__device__ __forceinline__ void gemm_core(
        const ushort_t* __restrict__ A, const ushort_t* __restrict__ B,
        ushort_t* __restrict__ Cb, float* __restrict__ Cf,
        const float* __restrict__ ep0, const float* __restrict__ ep1,
        int M, int N, int K, int KC) {
    constexpr int BM = 32 * TM;
    constexpr int BN = 32 * TN;
    constexpr int SEGS = BK / 8;
    constexpr int RSH  = (BK == 32) ? 1 : 0;
    constexpr int SSH  = (SEGS == 4) ? 2 : 3;
    __shared__ __align__(16) ushort_t As[BM * BK];
    __shared__ __align__(16) ushort_t Bs[BN * BK];

    const int tid  = threadIdx.x;
    const int lane = tid & 63;
    const int wave = tid >> 6;
    const int wm   = wave >> 1;
    const int wn   = wave & 1;
    const int q    = lane >> 4;
    const int l16  = lane & 15;

    const int tilesM = M / BM;
    const int tilesN = N / BN;
    int bid = (int)blockIdx.x;
    int sk = 0;
    if constexpr (SK4) { int nt = tilesM * tilesN; sk = bid / nt; bid = bid % nt; }
    const int xcd = bid & 7;
    const int j   = bid >> 3;
    const int bm  = xcd * (tilesM >> 3) + j / tilesN;
    const int bn  = j % tilesN;

    floatx4 acc[TM][TN];
    #pragma unroll
    for (int i = 0; i < TM; ++i)
        #pragma unroll
        for (int jj = 0; jj < TN; ++jj)
            acc[i][jj] = (floatx4){0.f, 0.f, 0.f, 0.f};

    const long aBase = (long)bm * BM * K + (long)sk * KC;
    const long bBase = (long)bn * BN * K + (long)sk * KC;
    const int  KLOOP = SK4 ? KC : K;

    for (int kt = 0; kt < KLOOP; kt += BK) {
        __syncthreads();
        #pragma unroll
        for (int i = 0; i < BM * BK / 2048; ++i) {
            int idx = tid + i * 256;
            int row = idx >> SSH, seg = idx & (SEGS - 1);
            int gseg = seg ^ ((row >> RSH) & (SEGS - 1));
            const ushort_t* g = A + aBase + (long)row * K + kt + gseg * 8;
            __builtin_amdgcn_global_load_lds(
                (const __attribute__((address_space(1))) void*)g,
                (__attribute__((address_space(3))) void*)(As + idx * 8),
                16, 0, 0);
        }
        #pragma unroll
        for (int i = 0; i < BN * BK / 2048; ++i) {
            int idx = tid + i * 256;
            int row = idx >> SSH, seg = idx & (SEGS - 1);
            int gseg = seg ^ ((row >> RSH) & (SEGS - 1));
            const ushort_t* g = B + bBase + (long)row * K + kt + gseg * 8;
            __builtin_amdgcn_global_load_lds(
                (const __attribute__((address_space(1))) void*)g,
                (__attribute__((address_space(3))) void*)(Bs + idx * 8),
                16, 0, 0);
        }
        __syncthreads();

        #pragma unroll
        for (int ks = 0; ks < BK / 32; ++ks) {
            short8 af[TM], bfr[TN];
            #pragma unroll
            for (int t = 0; t < TM; ++t) {
                int srow = wm * TM * 16 + t * 16 + l16;
                int rseg = (ks * 4 + q) ^ ((srow >> RSH) & (SEGS - 1));
                af[t] = *reinterpret_cast<const short8*>(&As[srow * BK + rseg * 8]);
            }
            #pragma unroll
            for (int t = 0; t < TN; ++t) {
                int srow = wn * TN * 16 + t * 16 + l16;
                int rseg = (ks * 4 + q) ^ ((srow >> RSH) & (SEGS - 1));
                bfr[t] = *reinterpret_cast<const short8*>(&Bs[srow * BK + rseg * 8]);
            }
            #pragma unroll
            for (int i = 0; i < TM; ++i)
                #pragma unroll
                for (int jj = 0; jj < TN; ++jj)
                    acc[i][jj] = __builtin_amdgcn_mfma_f32_16x16x32_bf16(
                        af[i], bfr[jj], acc[i][jj], 0, 0, 0);
        }
    }

    #pragma unroll
    for (int i = 0; i < TM; ++i) {
        #pragma unroll
        for (int jj = 0; jj < TN; ++jj) {
            #pragma unroll
            for (int r = 0; r < 4; ++r) {
                int row = bm * BM + wm * TM * 16 + i * 16 + q * 4 + r;
                int col = bn * BN + wn * TN * 16 + jj * 16 + l16;
                float v = acc[i][jj][r];
                if constexpr (EPI == 2) {
                    v += ep0[col];
                    v = v > 0.f ? v : 0.f;
                    Cb[(long)row * N + col] = f2bf(v);
                } else if constexpr (EPI == 3) {
                    const int half = N >> 1;
                    if (col < half)
                        Cf[(long)row * half + col] = v + ep0[col];
                    else
                        Cf[(long)M * half + (long)row * half + (col - half)] = v + ep1[col - half];
                } else {
                    Cf[(long)sk * M * N + (long)row * N + col] = v;
                }
            }
        }
    }
}

// =====================================================================
// R7: g2f with RESTORED pipeline depth (fix of R6's over-sync).
// Two named rA sets (rAa/rAb), unroll-by-2:
//   iter t: CVW(t+2) from set[t&1]   <- loads issued at iter t-2 (landed;
//           implicit compiler vmcnt leaves iter t-1's 6 VMEM in flight)
//           12 ds_read frags of tile t
//           STG_B(t+3) DMA; LDA(t+4) into set[t&1]
//           32 MFMA; lgkm(0); sched_barrier; [vmcnt(0) iff t==NT-2]; barrier
// Race-safety:
//  RAW A(t): CVW(t) at iter t-2, lgkm-drained before that barrier.
//  RAW B(t): rA(X) issued after STG_B(X-1)  =>  CVW(t+1)'s wait at iter
//            t-1 confirms B(t) landed; end-of-(t-1) barrier publishes.
//            Tail: B(NT-1) younger than all rA -> explicit vmcnt(0) at
//            iter NT-2.
//  WAR A-slot: CVW(t+2) hits slot (t-2)&3, reads drained 2 barriers ago.
//  WAR B-slot: DMA(t+3) hits slot (t-1)&3, reads drained 1 barrier ago.
// =====================================================================
__global__ __launch_bounds__(512, 2) void g2f(const float* __restrict__ Xf,
        const ushort_t* __restrict__ B, ushort_t* __restrict__ Cb,
        const float* __restrict__ bias, int M, int N, int K) {
    constexpr int BM = 256, BN = 256, BK = 32;
    __shared__ __align__(16) ushort_t As[4][BM * BK];   // 4 x 16 KiB
    __shared__ __align__(16) ushort_t Bs[4][BN * BK];   // 4 x 16 KiB

    const int tid  = threadIdx.x;       // 0..511
    const int lane = tid & 63;
    const int wave = tid >> 6;          // 0..7
    const int wm   = wave >> 2;         // 0..1  (M half: 128 rows)
    const int wn   = wave & 3;          // 0..3  (N quarter: 64 cols)
    const int q    = lane >> 4;
    const int l16  = lane & 15;

    const int tilesM = M / BM;          // 64
    const int tilesN = N / BN;          // 4
    int bid = (int)blockIdx.x;
    const int xcd = bid & 7;
    const int jb  = bid >> 3;
    const int bm  = xcd * (tilesM >> 3) + jb / tilesN;
    const int bn  = jb % tilesN;
    const int NT  = K / BK;             // 64 (even)

    const long aBase = (long)bm * BM * K;   // fp32 elements
    const long bBase = (long)bn * BN * K;   // bf16 elements

    floatx4 acc[8][4];
    #pragma unroll
    for (int i = 0; i < 8; ++i)
        #pragma unroll
        for (int j = 0; j < 4; ++j)
            acc[i][j] = (floatx4){0.f, 0.f, 0.f, 0.f};

    float4 rAa[4], rAb[4];   // two fp32 staging sets (16 VGPR each)

#define LDA(tt, RA) do {                                                            \
        _Pragma("unroll")                                                           \
        for (int _g = 0; _g < 2; ++_g) {                                            \
            int _idx = _g * 512 + tid;                                              \
            int _row = _idx >> 2, _seg = _idx & 3;                                  \
            int _gs = _seg ^ ((_row >> 1) & 3);                                     \
            const float4* _p = reinterpret_cast<const float4*>(                     \
                Xf + aBase + (long)_row * K + (tt) * BK + _gs * 8);                 \
            RA[2 * _g]     = _p[0];                                                 \
            RA[2 * _g + 1] = _p[1];                                                 \
        } } while (0)

#define CVW(tt, RA) do { const int _sl = (tt) & 3;                                  \
        _Pragma("unroll")                                                           \
        for (int _g = 0; _g < 2; ++_g) {                                            \
            int _idx = _g * 512 + tid;                                              \
            float4 _a = RA[2 * _g], _b = RA[2 * _g + 1];                            \
            short8 _o;                                                              \
            _o[0] = (short)f2bf(_a.x); _o[1] = (short)f2bf(_a.y);                   \
            _o[2] = (short)f2bf(_a.z); _o[3] = (short)f2bf(_a.w);                   \
            _o[4] = (short)f2bf(_b.x); _o[5] = (short)f2bf(_b.y);                   \
            _o[6] = (short)f2bf(_b.z); _o[7] = (short)f2bf(_b.w);                   \
            *reinterpret_cast<short8*>(&As[_sl][_idx * 8]) = _o;                    \
        } } while (0)

#define STG_B(tt) do { const int _sl = (tt) & 3;                                    \
        _Pragma("unroll")                                                           \
        for (int _g = 0; _g < 2; ++_g) {                                            \
            int _idx = _g * 512 + tid;                                              \
            int _row = _idx >> 2, _seg = _idx & 3;                                  \
            int _gs = _seg ^ ((_row >> 1) & 3);                                     \
            const ushort_t* _gp = B + bBase + (long)_row * K + (tt) * BK + _gs * 8; \
            __builtin_amdgcn_global_load_lds(                                       \
                (const __attribute__((address_space(1))) void*)_gp,                 \
                (__attribute__((address_space(3))) void*)(&Bs[_sl][_idx * 8]),      \
                16, 0, 0);                                                          \
        } } while (0)

    // one K-tile iteration (RA = this parity's register set)
#define ITER(tt, RA) do {                                                           \
        const int _slot = (tt) & 3;                                                 \
        if ((tt) + 2 < NT) CVW((tt) + 2, RA);                                       \
        short8 _bf[4], _alo[4], _ahi[4];                                            \
        _Pragma("unroll")                                                           \
        for (int _j = 0; _j < 4; ++_j) {                                            \
            int _sr = wn * 64 + _j * 16 + l16;                                      \
            int _rs = q ^ ((_sr >> 1) & 3);                                         \
            _bf[_j] = *reinterpret_cast<const short8*>(&Bs[_slot][_sr * BK + _rs * 8]); \
        }                                                                           \
        _Pragma("unroll")                                                           \
        for (int _i = 0; _i < 4; ++_i) {                                            \
            int _sr = wm * 128 + _i * 16 + l16;                                     \
            int _rs = q ^ ((_sr >> 1) & 3);                                         \
            _alo[_i] = *reinterpret_cast<const short8*>(&As[_slot][_sr * BK + _rs * 8]); \
        }                                                                           \
        _Pragma("unroll")                                                           \
        for (int _i = 0; _i < 4; ++_i) {                                            \
            int _sr = wm * 128 + 64 + _i * 16 + l16;                                \
            int _rs = q ^ ((_sr >> 1) & 3);                                         \
            _ahi[_i] = *reinterpret_cast<const short8*>(&As[_slot][_sr * BK + _rs * 8]); \
        }                                                                           \
        if ((tt) + 3 < NT) STG_B((tt) + 3);                                         \
        if ((tt) + 4 < NT) LDA((tt) + 4, RA);                                       \
        __builtin_amdgcn_s_setprio(1);                                              \
        _Pragma("unroll")                                                           \
        for (int _i = 0; _i < 4; ++_i)                                              \
            _Pragma("unroll")                                                       \
            for (int _j = 0; _j < 4; ++_j)                                          \
                acc[_i][_j] = __builtin_amdgcn_mfma_f32_16x16x32_bf16(              \
                    _alo[_i], _bf[_j], acc[_i][_j], 0, 0, 0);                       \
        _Pragma("unroll")                                                           \
        for (int _i = 0; _i < 4; ++_i)                                              \
            _Pragma("unroll")                                                       \
            for (int _j = 0; _j < 4; ++_j)                                          \
                acc[4 + _i][_j] = __builtin_amdgcn_mfma_f32_16x16x32_bf16(          \
                    _ahi[_i], _bf[_j], acc[4 + _i][_j], 0, 0, 0);                   \
        __builtin_amdgcn_s_setprio(0);                                              \
        asm volatile("s_waitcnt lgkmcnt(0)" ::: "memory");                          \
        __builtin_amdgcn_sched_barrier(0);                                          \
        if ((tt) == NT - 2)                                                         \
            asm volatile("s_waitcnt vmcnt(0)" ::: "memory");                        \
        __builtin_amdgcn_s_barrier();                                               \
        asm volatile("" ::: "memory");                                              \
    } while (0)

    // prologue: A(0),A(1) converted+written directly; rAa=A(2), rAb=A(3);
    // B(0..2) DMA'd.  vmcnt(4): forces LDA(2),LDA(3),B(0) done; B(1),B(2)
    // (4 youngest ops) stay in flight.
    LDA(0, rAa); CVW(0, rAa);
    LDA(1, rAb); CVW(1, rAb);
    LDA(2, rAa); LDA(3, rAb);
    STG_B(0); STG_B(1); STG_B(2);
    asm volatile("s_waitcnt lgkmcnt(0)" ::: "memory");
    asm volatile("s_waitcnt vmcnt(4)" ::: "memory");
    __builtin_amdgcn_s_barrier();
    asm volatile("" ::: "memory");

    for (int t = 0; t < NT; t += 2) {
        ITER(t, rAa);
        ITER(t + 1, rAb);
    }

#undef ITER
#undef STG_B
#undef CVW
#undef LDA

    // epilogue: bias + relu -> bf16
    float bsv[4];
    #pragma unroll
    for (int j = 0; j < 4; ++j)
        bsv[j] = bias[bn * BN + wn * 64 + j * 16 + l16];
    #pragma unroll
    for (int i = 0; i < 8; ++i) {
        int row = bm * BM + wm * 128 + i * 16 + q * 4;
        #pragma unroll
        for (int j = 0; j < 4; ++j) {
            int col = bn * BN + wn * 64 + j * 16 + l16;
            #pragma unroll
            for (int r = 0; r < 4; ++r) {
                float v = acc[i][j][r] + bsv[j];
                v = v > 0.f ? v : 0.f;
                Cb[(long)(row + r) * N + col] = f2bf(v);
            }
        }
    }
}

// ---- 128x128 tile pipelined core: 256 thr (4 waves 2x2), BK=32, ring-4 (64 KiB) ----
// EPI 2: +bias,relu->bf16 | 3: +bias split fp32 (mu|logvar)
template<int EPI>
__device__ __forceinline__ void gemm128_v2(
        const ushort_t* __restrict__ A, const ushort_t* __restrict__ B,
        ushort_t* __restrict__ Cb, float* __restrict__ Cf,
        const float* __restrict__ ep0, const float* __restrict__ ep1,
        int M, int N, int K) {
    constexpr int BM = 128, BN = 128, BK = 32;
    __shared__ __align__(16) ushort_t As[4][BM * BK];   // 4 x 8 KiB
    __shared__ __align__(16) ushort_t Bs[4][BN * BK];   // 4 x 8 KiB

    const int tid  = threadIdx.x;
    const int lane = tid & 63;
    const int wave = tid >> 6;
    const int wm   = wave >> 1;
    const int wn   = wave & 1;
    const int q    = lane >> 4;
    const int l16  = lane & 15;

    const int tilesM = M / BM;
    const int tilesN = N / BN;
    int bid = (int)blockIdx.x;
    const int xcd = bid & 7;
    const int jb  = bid >> 3;
    const int bm  = xcd * (tilesM >> 3) + jb / tilesN;
    const int bn  = jb % tilesN;
    const int NT  = K / BK;

    const long aBase = (long)bm * BM * K;
    const long bBase = (long)bn * BN * K;

    floatx4 acc[4][4];
    #pragma unroll
    for (int i = 0; i < 4; ++i)
        #pragma unroll
        for (int j = 0; j < 4; ++j)
            acc[i][j] = (floatx4){0.f, 0.f, 0.f, 0.f};

#define STAGE_A(t) do { int _sl = (t) & 3;                                          \
        _Pragma("unroll")                                                           \
        for (int _g = 0; _g < 2; ++_g) {                                            \
            int _idx = _g * 256 + tid;                                              \
            int _row = _idx >> 2, _seg = _idx & 3;                                  \
            int _gs = _seg ^ ((_row >> 1) & 3);                                     \
            const ushort_t* _gp = A + aBase + (long)_row * K + (t) * BK + _gs * 8;  \
            __builtin_amdgcn_global_load_lds(                                       \
                (const __attribute__((address_space(1))) void*)_gp,                 \
                (__attribute__((address_space(3))) void*)(&As[_sl][_idx * 8]),      \
                16, 0, 0);                                                          \
        } } while (0)
#define STAGE_B(t) do { int _sl = (t) & 3;                                          \
        _Pragma("unroll")                                                           \
        for (int _g = 0; _g < 2; ++_g) {                                            \
            int _idx = _g * 256 + tid;                                              \
            int _row = _idx >> 2, _seg = _idx & 3;                                  \
            int _gs = _seg ^ ((_row >> 1) & 3);                                     \
            const ushort_t* _gp = B + bBase + (long)_row * K + (t) * BK + _gs * 8;  \
            __builtin_amdgcn_global_load_lds(                                       \
                (const __attribute__((address_space(1))) void*)_gp,                 \
                (__attribute__((address_space(3))) void*)(&Bs[_sl][_idx * 8]),      \
                16, 0, 0);                                                          \
        } } while (0)

    STAGE_A(0); STAGE_B(0);
    STAGE_A(1); STAGE_B(1);
    STAGE_A(2); STAGE_B(2);
    asm volatile("s_waitcnt vmcnt(8)" ::: "memory");
    __builtin_amdgcn_s_barrier();
    asm volatile("" ::: "memory");

#define KTILE(tt, DOSTAGE, WAITOP) do {                                             \
        const int _slot = (tt) & 3;                                                 \
        short8 _bf[4], _af[4];                                                      \
        _Pragma("unroll")                                                           \
        for (int _j = 0; _j < 4; ++_j) {                                            \
            int _sr = wn * 64 + _j * 16 + l16;                                      \
            int _rs = q ^ ((_sr >> 1) & 3);                                         \
            _bf[_j] = *reinterpret_cast<const short8*>(&Bs[_slot][_sr * BK + _rs * 8]); \
        }                                                                           \
        _Pragma("unroll")                                                           \
        for (int _i = 0; _i < 4; ++_i) {                                            \
            int _sr = wm * 64 + _i * 16 + l16;                                      \
            int _rs = q ^ ((_sr >> 1) & 3);                                         \
            _af[_i] = *reinterpret_cast<const short8*>(&As[_slot][_sr * BK + _rs * 8]); \
        }                                                                           \
        if (DOSTAGE) { STAGE_A((tt) + 3); STAGE_B((tt) + 3); }                      \
        __builtin_amdgcn_s_setprio(1);                                              \
        _Pragma("unroll")                                                           \
        for (int _i = 0; _i < 4; ++_i)                                              \
            _Pragma("unroll")                                                       \
            for (int _j = 0; _j < 4; ++_j)                                          \
                acc[_i][_j] = __builtin_amdgcn_mfma_f32_16x16x32_bf16(              \
                    _af[_i], _bf[_j], acc[_i][_j], 0, 0, 0);                        \
        __builtin_amdgcn_s_setprio(0);                                              \
        asm volatile("s_waitcnt lgkmcnt(0)" ::: "memory");                          \
        __builtin_amdgcn_sched_barrier(0);                                          \
        WAITOP;                                                                     \
        __builtin_amdgcn_s_barrier();                                               \
        asm volatile("" ::: "memory");                                              \
    } while (0)

    int t = 0;
    for (; t < NT - 3; ++t) {
        KTILE(t, true, asm volatile("s_waitcnt vmcnt(8)" ::: "memory"));
    }
    KTILE(t, false, asm volatile("s_waitcnt vmcnt(4)" ::: "memory")); ++t;
    KTILE(t, false, asm volatile("s_waitcnt vmcnt(0)" ::: "memory")); ++t;
    KTILE(t, false, (void)0);

#undef KTILE
#undef STAGE_A
#undef STAGE_B

    #pragma unroll
    for (int i = 0; i < 4; ++i) {
        #pragma unroll
        for (int jj = 0; jj < 4; ++jj) {
            #pragma unroll
            for (int r = 0; r < 4; ++r) {
                int row = bm * BM + wm * 64 + i * 16 + q * 4 + r;
                int col = bn * BN + wn * 64 + jj * 16 + l16;
                float v = acc[i][jj][r];
                if constexpr (EPI == 2) {
                    v += ep0[col];
                    v = v > 0.f ? v : 0.f;
                    Cb[(long)row * N + col] = f2bf(v);
                } else {
                    const int half = N >> 1;
                    v += (col < half) ? ep0[col] : ep1[col - half];
                    if (col < half)
                        Cf[(long)row * half + col] = v;
                    else
                        Cf[(long)M * half + (long)row * half + (col - half)] = v;
                }
            }
        }
    }
}

// named wrappers (rocprof per-stage attribution)
__global__ __launch_bounds__(256) void g0p_sk(const ushort_t* A, const ushort_t* B,
        float* P, int M, int N, int K, int KC) {
    gemm_core<4, 4, 32, 4, true>(A, B, nullptr, P, nullptr, nullptr, M, N, K, KC);
}
__global__ __launch_bounds__(256) void g1p_sk(const ushort_t* A, const ushort_t* B,
        float* P, int M, int N, int K, int KC) {
    gemm_core<4, 4, 32, 4, true>(A, B, nullptr, P, nullptr, nullptr, M, N, K, KC);
}
__global__ __launch_bounds__(256, 2) void g3_h2(const ushort_t* A, const ushort_t* B,
        ushort_t* Cb, const float* ep0, int M, int N, int K) {
    gemm128_v2<2>(A, B, Cb, nullptr, ep0, nullptr, M, N, K);
}
__global__ __launch_bounds__(256, 2) void g4_head(const ushort_t* A, const ushort_t* B,
        float* Cf, const float* ep0, const float* ep1, int M, int N, int K) {
    gemm128_v2<3>(A, B, nullptr, Cf, ep0, ep1, M, N, K);
}

extern "C" void kernel_launch(void* const* d_in, const int* in_sizes, int n_in,
                              void* d_out, int out_size, void* d_ws, size_t ws_size,
                              hipStream_t stream) {
    const float* x   = (const float*)d_in[0];
    const float* fw  = (const float*)d_in[1];
    const float* kp  = (const float*)d_in[2];
    const float* W1  = (const float*)d_in[3];
    const float* b1  = (const float*)d_in[4];
    const float* W2  = (const float*)d_in[5];
    const float* b2  = (const float*)d_in[6];
    const float* Wmu = (const float*)d_in[7];
    const float* bmu = (const float*)d_in[8];
    const float* Wlv = (const float*)d_in[9];
    const float* blv = (const float*)d_in[10];
    float* out = (float*)d_out;

    char* ws = (char*)d_ws;
    const size_t MB = 1024 * 1024;
    // timeline-safe overlays (Xbf eliminated — g2f reads x directly):
    ushort_t* W1bf = (ushort_t*)(ws + 0);         //  4 MB   dead after g0p
    ushort_t* Dbf  = (ushort_t*)(ws + 4   * MB);  //  8 MB   dead after g0p
    ushort_t* Dtbf = (ushort_t*)(ws + 12  * MB);  //  8 MB   dead after g1p
    ushort_t* T1sT = (ushort_t*)(ws + 20  * MB);  //  4 MB   dead after g1p
    ushort_t* H1   = (ushort_t*)(ws + 0);         // 32 MB   written by g2f (overlays above)
    float*    P    = (float*)   (ws + 32  * MB);  // 32 MB   dead after k_red #2
    ushort_t* H2   = (ushort_t*)(ws + 96  * MB);  // 16 MB
    ushort_t* M1T  = (ushort_t*)(ws + 112 * MB);  //  4 MB
    ushort_t* W2bf = (ushort_t*)(ws + 116 * MB);  //  1 MB
    ushort_t* Wcat = (ushort_t*)(ws + 117 * MB);  // 0.5 MB
    float*    svec = (float*)   (ws + 118 * MB);  //  8 KB

    hipLaunchKernelGGL(k_scale, dim3(DIM / 256), dim3(256), 0, stream, fw, kp, svec);
    hipLaunchKernelGGL(k_gen_d, dim3(DIM * DIM / 256), dim3(256), 0, stream, Dbf, Dtbf);
    hipLaunchKernelGGL(k_cast_w, dim3((U_W1 + U_W2 + 2 * U_WH) / 256), dim3(256), 0, stream,
                       W1, W2, Wmu, Wlv, W1bf, W2bf, Wcat);

    // G0 (split-K=4): P[sk] = W1bf @ Dbf^T chunk   (1024 x 2048, KC=512)
    hipLaunchKernelGGL(g0p_sk, dim3(8 * 16 * 4), dim3(256), 0, stream,
                       W1bf, Dbf, P, 1024, 2048, 2048, 512);
    // reduce + scale -> T1sT
    hipLaunchKernelGGL(k_red, dim3(1024 * 2048 / 4 / 256), dim3(256), 0, stream,
                       P, T1sT, svec, 1024 * 2048 / 4, 2048 / 4);
    // G1 (split-K=4): P[sk] = T1sT @ Dtbf^T chunk  (1024 x 2048, KC=512)
    hipLaunchKernelGGL(g1p_sk, dim3(8 * 16 * 4), dim3(256), 0, stream,
                       T1sT, Dtbf, P, 1024, 2048, 2048, 512);
    // reduce -> M1T
    hipLaunchKernelGGL(k_red, dim3(1024 * 2048 / 4 / 256), dim3(256), 0, stream,
                       P, M1T, nullptr, 1024 * 2048 / 4, 2048 / 4);

    // G2 (fused X-cast, deep pipeline): H1 = relu(bf16(x) @ M1 + b1)
    hipLaunchKernelGGL(g2f, dim3((BATCH / 256) * (1024 / 256)), dim3(512), 0, stream,
                       x, M1T, H1, b1, BATCH, 1024, 2048);
    // G3: H2 = relu(H1 @ W2^T + b2)  (16384 x 512, K=1024) — 128² ring-4 pipelined
    hipLaunchKernelGGL(g3_h2, dim3((BATCH / 128) * (512 / 128)), dim3(256), 0, stream,
                       H1, W2bf, H2, b2, BATCH, 512, 1024);
    // G4: [mu | logvar] = H2 @ Wcat^T + bias, fp32 split (16384 x 512, K=512)
    hipLaunchKernelGGL(g4_head, dim3((BATCH / 128) * (512 / 128)), dim3(256), 0, stream,
                       H2, Wcat, out, bmu, blv, BATCH, 512, 512);

    (void)in_sizes; (void)n_in; (void)out_size; (void)ws_size;
}

// Round 8
// 364.376 us; speedup vs baseline: 1.0782x; 1.0337x over previous
//
#include <hip/hip_runtime.h>
#include <hip/hip_bf16.h>
#include <math.h>

#define DIM 2048
#define BATCH 16384

typedef __attribute__((ext_vector_type(8))) short short8;
typedef __attribute__((ext_vector_type(4))) short short4v;
typedef __attribute__((ext_vector_type(4))) float floatx4;
typedef unsigned short ushort_t;

__device__ __forceinline__ ushort_t f2bf(float f) {
    union { float f; unsigned u; } v; v.f = f;
    unsigned r = v.u + 0x7FFFu + ((v.u >> 16) & 1u);   // RNE
    return (ushort_t)(r >> 16);
}

// ---- merged prep: D/Dt generation + weight casts + band-scale (1 launch) ----
#define U_W1   262144
#define U_W2    65536
#define U_WH    16384
#define NB_GEND  (DIM * DIM / 256)          // 16384
#define NB_CASTW ((U_W1 + U_W2 + 2 * U_WH) / 256)   // 1408
__global__ void k_prep(const float* __restrict__ fw, const float* __restrict__ kp,
                       float* __restrict__ s,
                       ushort_t* __restrict__ D, ushort_t* __restrict__ Dt,
                       const float* __restrict__ W1, const float* __restrict__ W2,
                       const float* __restrict__ Wmu, const float* __restrict__ Wlv,
                       ushort_t* __restrict__ W1bf, ushort_t* __restrict__ W2bf,
                       ushort_t* __restrict__ Wcat) {
    int b = blockIdx.x;
    if (b < NB_GEND) {
        int idx = b * 256 + threadIdx.x;
        int r = idx >> 11;
        int c = idx & (DIM - 1);
        const float w  = 7.6699039394282058e-4f;  // pi/4096
        const float s0 = 0.02209708691207961f;    // sqrt(1/2048)
        const float s1 = 0.03125f;                // sqrt(2/2048)
        int m1 = ((2 * c + 1) * r) & (4 * DIM - 1);
        int m2 = ((2 * r + 1) * c) & (4 * DIM - 1);
        float v1 = __cosf(w * (float)m1) * (r == 0 ? s0 : s1);
        float v2 = __cosf(w * (float)m2) * (c == 0 ? s0 : s1);
        D[idx]  = f2bf(v1);
        Dt[idx] = f2bf(v2);
    } else if (b < NB_GEND + NB_CASTW) {
        int i = (b - NB_GEND) * 256 + threadIdx.x;
        const float* src; ushort_t* dst; int u;
        if (i < U_W1)                    { src = W1;  dst = W1bf;             u = i; }
        else if (i < U_W1 + U_W2)        { src = W2;  dst = W2bf;             u = i - U_W1; }
        else if (i < U_W1 + U_W2 + U_WH) { src = Wmu; dst = Wcat;             u = i - U_W1 - U_W2; }
        else                             { src = Wlv; dst = Wcat + 8 * U_WH;  u = i - U_W1 - U_W2 - U_WH; }
        const float4* p = reinterpret_cast<const float4*>(src) + 2 * (size_t)u;
        float4 a = p[0], bb = p[1];
        short8 r;
        r[0] = (short)f2bf(a.x);  r[1] = (short)f2bf(a.y);
        r[2] = (short)f2bf(a.z);  r[3] = (short)f2bf(a.w);
        r[4] = (short)f2bf(bb.x); r[5] = (short)f2bf(bb.y);
        r[6] = (short)f2bf(bb.z); r[7] = (short)f2bf(bb.w);
        *reinterpret_cast<short8*>(dst + 8 * (size_t)u) = r;
    } else {
        int n = (b - NB_GEND - NB_CASTW) * 256 + threadIdx.x;
        if (n < DIM) {
            float kv = kp[0];
            float f = 1.0f;
            for (int i = 0; i < 30; ++i) {
                long s0 = (long)((double)i       * (double)(DIM - 1) / 30.0);
                long e0 = (long)((double)(i + 1) * (double)(DIM - 1) / 30.0);
                if (n >= s0 && n < e0) {
                    if (e0 <= 30)
                        f = 1.0f + fw[i] * kv * (1.0f - (float)i / 30.0f);
                    else
                        f = 1.0f - fw[i] * kv * (1.0f - (float)(i - 30) / 30.0f);
                }
            }
            s[n] = f;
        }
    }
}

// ---- fp32 -> bf16 X cast ----
__global__ void k_cast_x(const float* __restrict__ in, ushort_t* __restrict__ out) {
    int i = blockIdx.x * blockDim.x + threadIdx.x;
    const float4* p = reinterpret_cast<const float4*>(in) + 2 * (size_t)i;
    float4 a = p[0], b = p[1];
    short8 r;
    r[0] = (short)f2bf(a.x); r[1] = (short)f2bf(a.y);
    r[2] = (short)f2bf(a.z); r[3] = (short)f2bf(a.w);
    r[4] = (short)f2bf(b.x); r[5] = (short)f2bf(b.y);
    r[6] = (short)f2bf(b.z); r[7] = (short)f2bf(b.w);
    *reinterpret_cast<short8*>(out + 8 * (size_t)i) = r;
}

// ---- split-K reduce: out = bf16( (P0+P1+P2+P3) [* scale[col]] ) ----
__global__ void k_red(const float* __restrict__ P, ushort_t* __restrict__ out,
                      const float* __restrict__ scale, int n4, int n4row) {
    int i = blockIdx.x * blockDim.x + threadIdx.x;   // float4 index
    const float4* p = reinterpret_cast<const float4*>(P);
    float4 a = p[i], b = p[i + n4], c = p[i + 2 * n4], d = p[i + 3 * n4];
    float4 s;
    s.x = a.x + b.x + c.x + d.x;
    s.y = a.y + b.y + c.y + d.y;
    s.z = a.z + b.z + c.z + d.z;
    s.w = a.w + b.w + c.w + d.w;
    if (scale) {
        float4 sc = reinterpret_cast<const float4*>(scale)[i & (n4row - 1)];
        s.x *= sc.x; s.y *= sc.y; s.z *= sc.z; s.w *= sc.w;
    }
    short4v o;
    o[0] = (short)f2bf(s.x); o[1] = (short)f2bf(s.y);
    o[2] = (short)f2bf(s.z); o[3] = (short)f2bf(s.w);
    *reinterpret_cast<short4v*>(out + 4 * (size_t)i) = o;
}

// =====================================================================
// 128x128 pipelined core (ring-4, 1 barrier/K-tile, proven R2 structure).
// EPI 2: +bias,relu->bf16 | 3: +bias split fp32 (mu|logvar)
// EPI 4 (SK4): fp32 partials to Cf + sk*M*N  (split-K=4 over KC chunks)
// =====================================================================
template<int EPI, bool SK4>
__device__ __forceinline__ void gemm128p(
        const ushort_t* __restrict__ A, const ushort_t* __restrict__ B,
        ushort_t* __restrict__ Cb, float* __restrict__ Cf,
        const float* __restrict__ ep0, const float* __restrict__ ep1,
        int M, int N, int K, int KC) {
    constexpr int BM = 128, BN = 128, BK = 32;
    __shared__ __align__(16) ushort_t As[4][BM * BK];   // 4 x 8 KiB
    __shared__ __align__(16) ushort_t Bs[4][BN * BK];   // 4 x 8 KiB

    const int tid  = threadIdx.x;
    const int lane = tid & 63;
    const int wave = tid >> 6;
    const int wm   = wave >> 1;
    const int wn   = wave & 1;
    const int q    = lane >> 4;
    const int l16  = lane & 15;

    const int tilesM = M / BM;
    const int tilesN = N / BN;
    int bid = (int)blockIdx.x;
    int sk = 0;
    if constexpr (SK4) { int nt = tilesM * tilesN; sk = bid / nt; bid = bid % nt; }
    const int xcd = bid & 7;
    const int jb  = bid >> 3;
    const int bm  = xcd * (tilesM >> 3) + jb / tilesN;
    const int bn  = jb % tilesN;
    const int NT  = (SK4 ? KC : K) / BK;

    const long aBase = (long)bm * BM * K + (long)sk * KC;
    const long bBase = (long)bn * BN * K + (long)sk * KC;

    floatx4 acc[4][4];
    #pragma unroll
    for (int i = 0; i < 4; ++i)
        #pragma unroll
        for (int j = 0; j < 4; ++j)
            acc[i][j] = (floatx4){0.f, 0.f, 0.f, 0.f};

#define STAGE_A(t) do { int _sl = (t) & 3;                                          \
        _Pragma("unroll")                                                           \
        for (int _g = 0; _g < 2; ++_g) {                                            \
            int _idx = _g * 256 + tid;                                              \
            int _row = _idx >> 2, _seg = _idx & 3;                                  \
            int _gs = _seg ^ ((_row >> 1) & 3);                                     \
            const ushort_t* _gp = A + aBase + (long)_row * K + (t) * BK + _gs * 8;  \
            __builtin_amdgcn_global_load_lds(                                       \
                (const __attribute__((address_space(1))) void*)_gp,                 \
                (__attribute__((address_space(3))) void*)(&As[_sl][_idx * 8]),      \
                16, 0, 0);                                                          \
        } } while (0)
#define STAGE_B(t) do { int _sl = (t) & 3;                                          \
        _Pragma("unroll")                                                           \
        for (int _g = 0; _g < 2; ++_g) {                                            \
            int _idx = _g * 256 + tid;                                              \
            int _row = _idx >> 2, _seg = _idx & 3;                                  \
            int _gs = _seg ^ ((_row >> 1) & 3);                                     \
            const ushort_t* _gp = B + bBase + (long)_row * K + (t) * BK + _gs * 8;  \
            __builtin_amdgcn_global_load_lds(                                       \
                (const __attribute__((address_space(1))) void*)_gp,                 \
                (__attribute__((address_space(3))) void*)(&Bs[_sl][_idx * 8]),      \
                16, 0, 0);                                                          \
        } } while (0)

    STAGE_A(0); STAGE_B(0);
    STAGE_A(1); STAGE_B(1);
    STAGE_A(2); STAGE_B(2);
    asm volatile("s_waitcnt vmcnt(8)" ::: "memory");
    __builtin_amdgcn_s_barrier();
    asm volatile("" ::: "memory");

#define KTILE(tt, DOSTAGE, WAITOP) do {                                             \
        const int _slot = (tt) & 3;                                                 \
        short8 _bf[4], _af[4];                                                      \
        _Pragma("unroll")                                                           \
        for (int _j = 0; _j < 4; ++_j) {                                            \
            int _sr = wn * 64 + _j * 16 + l16;                                      \
            int _rs = q ^ ((_sr >> 1) & 3);                                         \
            _bf[_j] = *reinterpret_cast<const short8*>(&Bs[_slot][_sr * BK + _rs * 8]); \
        }                                                                           \
        _Pragma("unroll")                                                           \
        for (int _i = 0; _i < 4; ++_i) {                                            \
            int _sr = wm * 64 + _i * 16 + l16;                                      \
            int _rs = q ^ ((_sr >> 1) & 3);                                         \
            _af[_i] = *reinterpret_cast<const short8*>(&As[_slot][_sr * BK + _rs * 8]); \
        }                                                                           \
        if (DOSTAGE) { STAGE_A((tt) + 3); STAGE_B((tt) + 3); }                      \
        __builtin_amdgcn_s_setprio(1);                                              \
        _Pragma("unroll")                                                           \
        for (int _i = 0; _i < 4; ++_i)                                              \
            _Pragma("unroll")                                                       \
            for (int _j = 0; _j < 4; ++_j)                                          \
                acc[_i][_j] = __builtin_amdgcn_mfma_f32_16x16x32_bf16(              \
                    _af[_i], _bf[_j], acc[_i][_j], 0, 0, 0);                        \
        __builtin_amdgcn_s_setprio(0);                                              \
        asm volatile("s_waitcnt lgkmcnt(0)" ::: "memory");                          \
        __builtin_amdgcn_sched_barrier(0);                                          \
        WAITOP;                                                                     \
        __builtin_amdgcn_s_barrier();                                               \
        asm volatile("" ::: "memory");                                              \
    } while (0)

    int t = 0;
    for (; t < NT - 3; ++t) {
        KTILE(t, true, asm volatile("s_waitcnt vmcnt(8)" ::: "memory"));
    }
    KTILE(t, false, asm volatile("s_waitcnt vmcnt(4)" ::: "memory")); ++t;
    KTILE(t, false, asm volatile("s_waitcnt vmcnt(0)" ::: "memory")); ++t;
    KTILE(t, false, (void)0);

#undef KTILE
#undef STAGE_A
#undef STAGE_B

    #pragma unroll
    for (int i = 0; i < 4; ++i) {
        #pragma unroll
        for (int jj = 0; jj < 4; ++jj) {
            #pragma unroll
            for (int r = 0; r < 4; ++r) {
                int row = bm * BM + wm * 64 + i * 16 + q * 4 + r;
                int col = bn * BN + wn * 64 + jj * 16 + l16;
                float v = acc[i][jj][r];
                if constexpr (EPI == 2) {
                    v += ep0[col];
                    v = v > 0.f ? v : 0.f;
                    Cb[(long)row * N + col] = f2bf(v);
                } else if constexpr (EPI == 3) {
                    const int half = N >> 1;
                    v += (col < half) ? ep0[col] : ep1[col - half];
                    if (col < half)
                        Cf[(long)row * half + col] = v;
                    else
                        Cf[(long)M * half + (long)row * half + (col - half)] = v;
                } else {   // EPI 4: split-K fp32 partial
                    Cf[(long)sk * M * N + (long)row * N + col] = v;
                }
            }
        }
    }
}

// =====================================================================
// g2f: fused fp32->bf16 A-cast GEMM (R7 structure, measured 108-110 us).
// =====================================================================
__global__ __launch_bounds__(512, 2) void g2f(const float* __restrict__ Xf,
        const ushort_t* __restrict__ B, ushort_t* __restrict__ Cb,
        const float* __restrict__ bias, int M, int N, int K) {
    constexpr int BM = 256, BN = 256, BK = 32;
    __shared__ __align__(16) ushort_t As[4][BM * BK];   // 4 x 16 KiB
    __shared__ __align__(16) ushort_t Bs[4][BN * BK];   // 4 x 16 KiB

    const int tid  = threadIdx.x;       // 0..511
    const int lane = tid & 63;
    const int wave = tid >> 6;          // 0..7
    const int wm   = wave >> 2;         // 0..1
    const int wn   = wave & 3;          // 0..3
    const int q    = lane >> 4;
    const int l16  = lane & 15;

    const int tilesM = M / BM;          // 64
    const int tilesN = N / BN;          // 4
    int bid = (int)blockIdx.x;
    const int xcd = bid & 7;
    const int jb  = bid >> 3;
    const int bm  = xcd * (tilesM >> 3) + jb / tilesN;
    const int bn  = jb % tilesN;
    const int NT  = K / BK;             // 64 (even)

    const long aBase = (long)bm * BM * K;   // fp32 elements
    const long bBase = (long)bn * BN * K;   // bf16 elements

    floatx4 acc[8][4];
    #pragma unroll
    for (int i = 0; i < 8; ++i)
        #pragma unroll
        for (int j = 0; j < 4; ++j)
            acc[i][j] = (floatx4){0.f, 0.f, 0.f, 0.f};

    float4 rAa[4], rAb[4];

#define LDA(tt, RA) do {                                                            \
        _Pragma("unroll")                                                           \
        for (int _g = 0; _g < 2; ++_g) {                                            \
            int _idx = _g * 512 + tid;                                              \
            int _row = _idx >> 2, _seg = _idx & 3;                                  \
            int _gs = _seg ^ ((_row >> 1) & 3);                                     \
            const float4* _p = reinterpret_cast<const float4*>(                     \
                Xf + aBase + (long)_row * K + (tt) * BK + _gs * 8);                 \
            RA[2 * _g]     = _p[0];                                                 \
            RA[2 * _g + 1] = _p[1];                                                 \
        } } while (0)

#define CVW(tt, RA) do { const int _sl = (tt) & 3;                                  \
        _Pragma("unroll")                                                           \
        for (int _g = 0; _g < 2; ++_g) {                                            \
            int _idx = _g * 512 + tid;                                              \
            float4 _a = RA[2 * _g], _b = RA[2 * _g + 1];                            \
            short8 _o;                                                              \
            _o[0] = (short)f2bf(_a.x); _o[1] = (short)f2bf(_a.y);                   \
            _o[2] = (short)f2bf(_a.z); _o[3] = (short)f2bf(_a.w);                   \
            _o[4] = (short)f2bf(_b.x); _o[5] = (short)f2bf(_b.y);                   \
            _o[6] = (short)f2bf(_b.z); _o[7] = (short)f2bf(_b.w);                   \
            *reinterpret_cast<short8*>(&As[_sl][_idx * 8]) = _o;                    \
        } } while (0)

#define STG_B(tt) do { const int _sl = (tt) & 3;                                    \
        _Pragma("unroll")                                                           \
        for (int _g = 0; _g < 2; ++_g) {                                            \
            int _idx = _g * 512 + tid;                                              \
            int _row = _idx >> 2, _seg = _idx & 3;                                  \
            int _gs = _seg ^ ((_row >> 1) & 3);                                     \
            const ushort_t* _gp = B + bBase + (long)_row * K + (tt) * BK + _gs * 8; \
            __builtin_amdgcn_global_load_lds(                                       \
                (const __attribute__((address_space(1))) void*)_gp,                 \
                (__attribute__((address_space(3))) void*)(&Bs[_sl][_idx * 8]),      \
                16, 0, 0);                                                          \
        } } while (0)

#define ITER(tt, RA) do {                                                           \
        const int _slot = (tt) & 3;                                                 \
        if ((tt) + 2 < NT) CVW((tt) + 2, RA);                                       \
        short8 _bf[4], _alo[4], _ahi[4];                                            \
        _Pragma("unroll")                                                           \
        for (int _j = 0; _j < 4; ++_j) {                                            \
            int _sr = wn * 64 + _j * 16 + l16;                                      \
            int _rs = q ^ ((_sr >> 1) & 3);                                         \
            _bf[_j] = *reinterpret_cast<const short8*>(&Bs[_slot][_sr * BK + _rs * 8]); \
        }                                                                           \
        _Pragma("unroll")                                                           \
        for (int _i = 0; _i < 4; ++_i) {                                            \
            int _sr = wm * 128 + _i * 16 + l16;                                     \
            int _rs = q ^ ((_sr >> 1) & 3);                                         \
            _alo[_i] = *reinterpret_cast<const short8*>(&As[_slot][_sr * BK + _rs * 8]); \
        }                                                                           \
        _Pragma("unroll")                                                           \
        for (int _i = 0; _i < 4; ++_i) {                                            \
            int _sr = wm * 128 + 64 + _i * 16 + l16;                                \
            int _rs = q ^ ((_sr >> 1) & 3);                                         \
            _ahi[_i] = *reinterpret_cast<const short8*>(&As[_slot][_sr * BK + _rs * 8]); \
        }                                                                           \
        if ((tt) + 3 < NT) STG_B((tt) + 3);                                         \
        if ((tt) + 4 < NT) LDA((tt) + 4, RA);                                       \
        __builtin_amdgcn_s_setprio(1);                                              \
        _Pragma("unroll")                                                           \
        for (int _i = 0; _i < 4; ++_i)                                              \
            _Pragma("unroll")                                                       \
            for (int _j = 0; _j < 4; ++_j)                                          \
                acc[_i][_j] = __builtin_amdgcn_mfma_f32_16x16x32_bf16(              \
                    _alo[_i], _bf[_j], acc[_i][_j], 0, 0, 0);                       \
        _Pragma("unroll")                                                           \
        for (int _i = 0; _i < 4; ++_i)                                              \
            _Pragma("unroll")                                                       \
            for (int _j = 0; _j < 4; ++_j)                                          \
                acc[4 + _i][_j] = __builtin_amdgcn_mfma_f32_16x16x32_bf16(          \
                    _ahi[_i], _bf[_j], acc[4 + _i][_j], 0, 0, 0);                   \
        __builtin_amdgcn_s_setprio(0);                                              \
        asm volatile("s_waitcnt lgkmcnt(0)" ::: "memory");                          \
        __builtin_amdgcn_sched_barrier(0);                                          \
        if ((tt) == NT - 2)                                                         \
            asm volatile("s_waitcnt vmcnt(0)" ::: "memory");                        \
        __builtin_amdgcn_s_barrier();                                               \
        asm volatile("" ::: "memory");                                              \
    } while (0)

    LDA(0, rAa); CVW(0, rAa);
    LDA(1, rAb); CVW(1, rAb);
    LDA(2, rAa); LDA(3, rAb);
    STG_B(0); STG_B(1); STG_B(2);
    asm volatile("s_waitcnt lgkmcnt(0)" ::: "memory");
    asm volatile("s_waitcnt vmcnt(4)" ::: "memory");
    __builtin_amdgcn_s_barrier();
    asm volatile("" ::: "memory");

    for (int t = 0; t < NT; t += 2) {
        ITER(t, rAa);
        ITER(t + 1, rAb);
    }

#undef ITER
#undef STG_B
#undef CVW
#undef LDA

    float bsv[4];
    #pragma unroll
    for (int j = 0; j < 4; ++j)
        bsv[j] = bias[bn * BN + wn * 64 + j * 16 + l16];
    #pragma unroll
    for (int i = 0; i < 8; ++i) {
        int row = bm * BM + wm * 128 + i * 16 + q * 4;
        #pragma unroll
        for (int j = 0; j < 4; ++j) {
            int col = bn * BN + wn * 64 + j * 16 + l16;
            #pragma unroll
            for (int r = 0; r < 4; ++r) {
                float v = acc[i][j][r] + bsv[j];
                v = v > 0.f ? v : 0.f;
                Cb[(long)(row + r) * N + col] = f2bf(v);
            }
        }
    }
}

// named wrappers (rocprof per-stage attribution)
__global__ __launch_bounds__(256, 2) void g0p_sk(const ushort_t* A, const ushort_t* B,
        float* P, int M, int N, int K, int KC) {
    gemm128p<4, true>(A, B, nullptr, P, nullptr, nullptr, M, N, K, KC);
}
__global__ __launch_bounds__(256, 2) void g1p_sk(const ushort_t* A, const ushort_t* B,
        float* P, int M, int N, int K, int KC) {
    gemm128p<4, true>(A, B, nullptr, P, nullptr, nullptr, M, N, K, KC);
}
__global__ __launch_bounds__(256, 2) void g3_h2(const ushort_t* A, const ushort_t* B,
        ushort_t* Cb, const float* ep0, int M, int N, int K) {
    gemm128p<2, false>(A, B, Cb, nullptr, ep0, nullptr, M, N, K, 0);
}
__global__ __launch_bounds__(256, 2) void g4_head(const ushort_t* A, const ushort_t* B,
        float* Cf, const float* ep0, const float* ep1, int M, int N, int K) {
    gemm128p<3, false>(A, B, nullptr, Cf, ep0, ep1, M, N, K, 0);
}

extern "C" void kernel_launch(void* const* d_in, const int* in_sizes, int n_in,
                              void* d_out, int out_size, void* d_ws, size_t ws_size,
                              hipStream_t stream) {
    const float* x   = (const float*)d_in[0];
    const float* fw  = (const float*)d_in[1];
    const float* kp  = (const float*)d_in[2];
    const float* W1  = (const float*)d_in[3];
    const float* b1  = (const float*)d_in[4];
    const float* W2  = (const float*)d_in[5];
    const float* b2  = (const float*)d_in[6];
    const float* Wmu = (const float*)d_in[7];
    const float* bmu = (const float*)d_in[8];
    const float* Wlv = (const float*)d_in[9];
    const float* blv = (const float*)d_in[10];
    float* out = (float*)d_out;

    char* ws = (char*)d_ws;
    const size_t MB = 1024 * 1024;
    // timeline-safe overlays (Xbf eliminated — g2f reads x directly):
    ushort_t* W1bf = (ushort_t*)(ws + 0);         //  4 MB   dead after g0p
    ushort_t* Dbf  = (ushort_t*)(ws + 4   * MB);  //  8 MB   dead after g0p
    ushort_t* Dtbf = (ushort_t*)(ws + 12  * MB);  //  8 MB   dead after g1p
    ushort_t* T1sT = (ushort_t*)(ws + 20  * MB);  //  4 MB   dead after g1p
    ushort_t* H1   = (ushort_t*)(ws + 0);         // 32 MB   written by g2f (overlays above)
    float*    P    = (float*)   (ws + 32  * MB);  // 32 MB   dead after k_red #2
    ushort_t* H2   = (ushort_t*)(ws + 96  * MB);  // 16 MB
    ushort_t* M1T  = (ushort_t*)(ws + 112 * MB);  //  4 MB
    ushort_t* W2bf = (ushort_t*)(ws + 116 * MB);  //  1 MB
    ushort_t* Wcat = (ushort_t*)(ws + 117 * MB);  // 0.5 MB
    float*    svec = (float*)   (ws + 118 * MB);  //  8 KB

    // merged prep: D/Dt + weight casts + band scale (1 launch)
    hipLaunchKernelGGL(k_prep, dim3(NB_GEND + NB_CASTW + DIM / 256), dim3(256), 0, stream,
                       fw, kp, svec, Dbf, Dtbf, W1, W2, Wmu, Wlv, W1bf, W2bf, Wcat);

    // G0 (split-K=4, pipelined): P[sk] = W1bf @ Dbf^T chunk   (1024 x 2048, KC=512)
    hipLaunchKernelGGL(g0p_sk, dim3(8 * 16 * 4), dim3(256), 0, stream,
                       W1bf, Dbf, P, 1024, 2048, 2048, 512);
    // reduce + scale -> T1sT
    hipLaunchKernelGGL(k_red, dim3(1024 * 2048 / 4 / 256), dim3(256), 0, stream,
                       P, T1sT, svec, 1024 * 2048 / 4, 2048 / 4);
    // G1 (split-K=4, pipelined): P[sk] = T1sT @ Dtbf^T chunk  (1024 x 2048, KC=512)
    hipLaunchKernelGGL(g1p_sk, dim3(8 * 16 * 4), dim3(256), 0, stream,
                       T1sT, Dtbf, P, 1024, 2048, 2048, 512);
    // reduce -> M1T
    hipLaunchKernelGGL(k_red, dim3(1024 * 2048 / 4 / 256), dim3(256), 0, stream,
                       P, M1T, nullptr, 1024 * 2048 / 4, 2048 / 4);

    // G2 (fused X-cast): H1 = relu(bf16(x) @ M1 + b1)   (16384 x 1024, K=2048)
    hipLaunchKernelGGL(g2f, dim3((BATCH / 256) * (1024 / 256)), dim3(512), 0, stream,
                       x, M1T, H1, b1, BATCH, 1024, 2048);
    // G3: H2 = relu(H1 @ W2^T + b2)  (16384 x 512, K=1024)
    hipLaunchKernelGGL(g3_h2, dim3((BATCH / 128) * (512 / 128)), dim3(256), 0, stream,
                       H1, W2bf, H2, b2, BATCH, 512, 1024);
    // G4: [mu | logvar] = H2 @ Wcat^T + bias, fp32 split (16384 x 512, K=512)
    hipLaunchKernelGGL(g4_head, dim3((BATCH / 128) * (512 / 128)), dim3(256), 0, stream,
                       H2, Wcat, out, bmu, blv, BATCH, 512, 512);

    (void)in_sizes; (void)n_in; (void)out_size; (void)ws_size;
}